// Round 1
// baseline (2494.672 us; speedup 1.0000x reference)
//
#include <hip/hip_runtime.h>
#include <math.h>

// ---------------- kernels ----------------

__global__ void k_fill(float* __restrict__ p, float v, int n) {
    int i = blockIdx.x * blockDim.x + threadIdx.x;
    int s = gridDim.x * blockDim.x;
    for (; i < n; i += s) p[i] = v;
}

// deg[dst] += ew[e]  (deg pre-filled with 1.0 for self-loop)
__global__ void k_deg_edges(const int* __restrict__ ei, const float* __restrict__ ew,
                            float* __restrict__ deg, int E) {
    int i = blockIdx.x * blockDim.x + threadIdx.x;
    int s = gridDim.x * blockDim.x;
    for (; i < E; i += s) {
        int dst = ei[E + i];
        unsafeAtomicAdd(&deg[dst], ew[i]);
    }
}

__global__ void k_inv_sqrt(float* __restrict__ p, int n) {
    int i = blockIdx.x * blockDim.x + threadIdx.x;
    int s = gridDim.x * blockDim.x;
    for (; i < n; i += s) p[i] = 1.0f / sqrtf(p[i]);
}

// out[node][f] = sum_k X[node][k] * W[k][f], W staged in LDS (K x 64)
template <int K>
__global__ void k_gemm(const float* __restrict__ X, const float* __restrict__ W,
                       float* __restrict__ out, int n_nodes) {
    __shared__ float sW[K * 64];
    for (int i = threadIdx.x; i < K * 64; i += blockDim.x) sW[i] = W[i];
    __syncthreads();
    int f = threadIdx.x & 63;
    int local = threadIdx.x >> 6;                 // 0..3 (256 threads = 4 waves)
    int nper = blockDim.x >> 6;
    for (int node = blockIdx.x * nper + local; node < n_nodes; node += gridDim.x * nper) {
        const float* xr = X + (size_t)node * K;
        float acc = 0.f;
#pragma unroll 8
        for (int k = 0; k < K; ++k) acc += xr[k] * sW[k * 64 + f];
        out[(size_t)node * 64 + f] = acc;
    }
}

// Q[n][f] = b[f] + dinv[n]^2 * P[n][f]   (self-loop term + bias)
__global__ void k_init_out(const float* __restrict__ P, const float* __restrict__ dinv,
                           const float* __restrict__ b, float* __restrict__ Q, int n_nodes) {
    int total = n_nodes * 64;
    int i = blockIdx.x * blockDim.x + threadIdx.x;
    int s = gridDim.x * blockDim.x;
    for (; i < total; i += s) {
        int n = i >> 6, f = i & 63;
        float d = dinv[n];
        Q[i] = b[f] + d * d * P[i];
    }
}

// one wave per edge: Q[dst][lane] += dinv[src]*ew*dinv[dst] * P[src][lane]
__global__ void k_scatter(const int* __restrict__ ei, const float* __restrict__ ew,
                          const float* __restrict__ dinv, const float* __restrict__ P,
                          float* __restrict__ Q, int E) {
    int lane = threadIdx.x & 63;
    int w = blockIdx.x * (blockDim.x >> 6) + (threadIdx.x >> 6);
    int nw = gridDim.x * (blockDim.x >> 6);
    for (int e = w; e < E; e += nw) {
        int src = ei[e];
        int dst = ei[E + e];
        float nrm = dinv[src] * ew[e] * dinv[dst];
        float v = nrm * P[(size_t)src * 64 + lane];
        unsafeAtomicAdd(&Q[(size_t)dst * 64 + lane], v);
    }
}

// in-place row L2-normalize then ReLU; one wave per node
__global__ void k_l2relu(float* __restrict__ Q, int n_nodes) {
    int lane = threadIdx.x & 63;
    int w = blockIdx.x * (blockDim.x >> 6) + (threadIdx.x >> 6);
    int nw = gridDim.x * (blockDim.x >> 6);
    for (int n = w; n < n_nodes; n += nw) {
        float v = Q[(size_t)n * 64 + lane];
        float ss = v * v;
#pragma unroll
        for (int off = 32; off; off >>= 1) ss += __shfl_xor(ss, off, 64);
        float nrm = sqrtf(ss);
        float out = v / fmaxf(nrm, 1e-12f);
        Q[(size_t)n * 64 + lane] = fmaxf(out, 0.f);
    }
}

// pooled[batch[n]][lane] += Q[n][lane]
__global__ void k_pool(const float* __restrict__ Q, const int* __restrict__ batch,
                       float* __restrict__ pooled, int n_nodes) {
    int lane = threadIdx.x & 63;
    int w = blockIdx.x * (blockDim.x >> 6) + (threadIdx.x >> 6);
    int nw = gridDim.x * (blockDim.x >> 6);
    for (int n = w; n < n_nodes; n += nw) {
        int g = batch[n];
        unsafeAtomicAdd(&pooled[(size_t)g * 64 + lane], Q[(size_t)n * 64 + lane]);
    }
}

// per-graph MLP: relu(pooled@fc1+b) @ fc2 + b2, then log_softmax over 10
__global__ void k_mlp(const float* __restrict__ pooled,
                      const float* __restrict__ fc1w, const float* __restrict__ fc1b,
                      const float* __restrict__ fc2w, const float* __restrict__ fc2b,
                      float* __restrict__ out, int G) {
    __shared__ float sp[64];
    __shared__ float sz[64];
    __shared__ float sl[10];
    __shared__ float slse;
    int g = blockIdx.x;
    int t = threadIdx.x;
    if (g >= G) return;
    sp[t] = pooled[(size_t)g * 64 + t];
    __syncthreads();
    float acc = fc1b[t];
#pragma unroll
    for (int k = 0; k < 64; ++k) acc += sp[k] * fc1w[k * 64 + t];
    sz[t] = fmaxf(acc, 0.f);
    __syncthreads();
    if (t < 10) {
        float a = fc2b[t];
#pragma unroll
        for (int j = 0; j < 64; ++j) a += sz[j] * fc2w[j * 10 + t];
        sl[t] = a;
    }
    __syncthreads();
    if (t == 0) {
        float m = sl[0];
        for (int c = 1; c < 10; ++c) m = fmaxf(m, sl[c]);
        float s = 0.f;
        for (int c = 0; c < 10; ++c) s += expf(sl[c] - m);
        slse = m + logf(s);
    }
    __syncthreads();
    if (t < 10) out[(size_t)g * 10 + t] = sl[t] - slse;
}

// ---------------- launch ----------------

extern "C" void kernel_launch(void* const* d_in, const int* in_sizes, int n_in,
                              void* d_out, int out_size, void* d_ws, size_t ws_size,
                              hipStream_t stream) {
    const float* x     = (const float*)d_in[0];
    const int*   ei    = (const int*)d_in[1];
    const int*   batch = (const int*)d_in[2];
    const float* ew    = (const float*)d_in[3];
    const float* W1 = (const float*)d_in[4];
    const float* b1 = (const float*)d_in[5];
    const float* W2 = (const float*)d_in[6];
    const float* b2 = (const float*)d_in[7];
    const float* W3 = (const float*)d_in[8];
    const float* b3 = (const float*)d_in[9];
    const float* fc1w = (const float*)d_in[10];
    const float* fc1b = (const float*)d_in[11];
    const float* fc2w = (const float*)d_in[12];
    const float* fc2b = (const float*)d_in[13];
    float* out = (float*)d_out;

    const int N = in_sizes[0] / 128;   // 100000
    const int E = in_sizes[1] / 2;     // 3200000
    const int G = out_size / 10;       // 512

    float* P      = (float*)d_ws;                    // N*64
    float* Q      = P + (size_t)N * 64;              // N*64
    float* dinv   = Q + (size_t)N * 64;              // N
    float* pooled = dinv + N;                        // G*64

    const int BT = 256;
    dim3 blk(BT);
    dim3 g2048(2048), g8192(8192);
    dim3 gG(G);
    dim3 blk64(64);

    // degree -> dinv
    k_fill<<<dim3(512), blk, 0, stream>>>(dinv, 1.0f, N);
    k_deg_edges<<<g2048, blk, 0, stream>>>(ei, ew, dinv, E);
    k_inv_sqrt<<<dim3(512), blk, 0, stream>>>(dinv, N);

    // conv1: K=128, input x
    k_gemm<128><<<g2048, blk, 0, stream>>>(x, W1, P, N);
    k_init_out<<<g2048, blk, 0, stream>>>(P, dinv, b1, Q, N);
    k_scatter<<<g8192, blk, 0, stream>>>(ei, ew, dinv, P, Q, E);
    k_l2relu<<<g2048, blk, 0, stream>>>(Q, N);

    // conv2: K=64, input Q -> P -> Q
    k_gemm<64><<<g2048, blk, 0, stream>>>(Q, W2, P, N);
    k_init_out<<<g2048, blk, 0, stream>>>(P, dinv, b2, Q, N);
    k_scatter<<<g8192, blk, 0, stream>>>(ei, ew, dinv, P, Q, E);
    k_l2relu<<<g2048, blk, 0, stream>>>(Q, N);

    // conv3
    k_gemm<64><<<g2048, blk, 0, stream>>>(Q, W3, P, N);
    k_init_out<<<g2048, blk, 0, stream>>>(P, dinv, b3, Q, N);
    k_scatter<<<g8192, blk, 0, stream>>>(ei, ew, dinv, P, Q, E);
    k_l2relu<<<g2048, blk, 0, stream>>>(Q, N);

    // pool + MLP
    k_fill<<<dim3(64), blk, 0, stream>>>(pooled, 0.0f, G * 64);
    k_pool<<<g2048, blk, 0, stream>>>(Q, batch, pooled, N);
    k_mlp<<<gG, blk64, 0, stream>>>(pooled, fc1w, fc1b, fc2w, fc2b, out, G);
}

// Round 2
// 1278.475 us; speedup vs baseline: 1.9513x; 1.9513x over previous
//
#include <hip/hip_runtime.h>
#include <math.h>

// ---------------- utility fills ----------------

__global__ void k_fill_f(float* __restrict__ p, float v, int n) {
    int i = blockIdx.x * blockDim.x + threadIdx.x;
    int s = gridDim.x * blockDim.x;
    for (; i < n; i += s) p[i] = v;
}

__global__ void k_fill_i(int* __restrict__ p, int v, int n) {
    int i = blockIdx.x * blockDim.x + threadIdx.x;
    int s = gridDim.x * blockDim.x;
    for (; i < n; i += s) p[i] = v;
}

// ---------------- degree + histogram (one pass over edges) ----------------

__global__ void k_deg_hist(const int* __restrict__ ei, const float* __restrict__ ew,
                           float* __restrict__ deg, int* __restrict__ cnt, int E) {
    int i = blockIdx.x * blockDim.x + threadIdx.x;
    int s = gridDim.x * blockDim.x;
    for (; i < E; i += s) {
        int dst = ei[E + i];
        unsafeAtomicAdd(&deg[dst], ew[i]);
        atomicAdd(&cnt[dst], 1);
    }
}

__global__ void k_inv_sqrt(float* __restrict__ p, int n) {
    int i = blockIdx.x * blockDim.x + threadIdx.x;
    int s = gridDim.x * blockDim.x;
    for (; i < n; i += s) p[i] = 1.0f / sqrtf(p[i]);
}

// ---------------- exclusive scan (single 1024-thread block) ----------------

__global__ void k_scan(const int* __restrict__ cnt, int* __restrict__ row_ptr,
                       int* __restrict__ cursor, int n) {
    __shared__ int ssum[1024];
    int t = threadIdx.x;
    int chunk = (n + 1023) / 1024;
    int lo = t * chunk;
    int hi = lo + chunk; if (hi > n) hi = n; if (lo > n) lo = n;
    int s = 0;
    for (int i = lo; i < hi; ++i) s += cnt[i];
    ssum[t] = s;
    __syncthreads();
    for (int off = 1; off < 1024; off <<= 1) {
        int v = (t >= off) ? ssum[t - off] : 0;
        __syncthreads();
        ssum[t] += v;
        __syncthreads();
    }
    int base = (t == 0) ? 0 : ssum[t - 1];
    for (int i = lo; i < hi; ++i) {
        int c = cnt[i];
        row_ptr[i] = base;
        cursor[i] = base;
        base += c;
    }
    if (t == 1023) row_ptr[n] = ssum[1023];
}

// ---------------- CSR fill: meta[pos] = (src, norm) ----------------

__global__ void k_fill_edges(const int* __restrict__ ei, const float* __restrict__ ew,
                             const float* __restrict__ dinv, int* __restrict__ cursor,
                             int2* __restrict__ meta, int E) {
    int i = blockIdx.x * blockDim.x + threadIdx.x;
    int s = gridDim.x * blockDim.x;
    for (; i < E; i += s) {
        int src = ei[i];
        int dst = ei[E + i];
        int pos = atomicAdd(&cursor[dst], 1);
        float w = dinv[src] * ew[i] * dinv[dst];
        meta[pos] = make_int2(src, __float_as_int(w));
    }
}

// ---------------- dense H@W, W staged in LDS ----------------

template <int K>
__global__ void k_gemm(const float* __restrict__ X, const float* __restrict__ W,
                       float* __restrict__ out, int n_nodes) {
    __shared__ float sW[K * 64];
    for (int i = threadIdx.x; i < K * 64; i += blockDim.x) sW[i] = W[i];
    __syncthreads();
    int f = threadIdx.x & 63;
    int local = threadIdx.x >> 6;
    int nper = blockDim.x >> 6;
    for (int node = blockIdx.x * nper + local; node < n_nodes; node += gridDim.x * nper) {
        const float* xr = X + (size_t)node * K;
        float acc = 0.f;
#pragma unroll 8
        for (int k = 0; k < K; ++k) acc += xr[k] * sW[k * 64 + f];
        out[(size_t)node * 64 + f] = acc;
    }
}

// ---------------- fused gather-conv: self-loop + neighbors + bias + l2norm + relu ----------------
// one wave per destination node; lane = feature

template <bool POOL>
__global__ void k_conv(const float* __restrict__ P, const int* __restrict__ row_ptr,
                       const int2* __restrict__ meta, const float* __restrict__ dinv,
                       const float* __restrict__ b, const int* __restrict__ batch,
                       float* __restrict__ Q, float* __restrict__ pooled, int n_nodes) {
    int lane = threadIdx.x & 63;
    int w = blockIdx.x * (blockDim.x >> 6) + (threadIdx.x >> 6);
    int nw = gridDim.x * (blockDim.x >> 6);
    for (int nd = w; nd < n_nodes; nd += nw) {
        float d = dinv[nd];
        float acc = d * d * P[(size_t)nd * 64 + lane];
        int beg = row_ptr[nd], end = row_ptr[nd + 1];
        int e = beg;
        for (; e + 3 < end; e += 4) {
            int2 m0 = meta[e], m1 = meta[e + 1], m2 = meta[e + 2], m3 = meta[e + 3];
            float p0 = P[(size_t)m0.x * 64 + lane];
            float p1 = P[(size_t)m1.x * 64 + lane];
            float p2 = P[(size_t)m2.x * 64 + lane];
            float p3 = P[(size_t)m3.x * 64 + lane];
            acc += __int_as_float(m0.y) * p0;
            acc += __int_as_float(m1.y) * p1;
            acc += __int_as_float(m2.y) * p2;
            acc += __int_as_float(m3.y) * p3;
        }
        for (; e < end; ++e) {
            int2 m = meta[e];
            acc += __int_as_float(m.y) * P[(size_t)m.x * 64 + lane];
        }
        acc += b[lane];
        float ss = acc * acc;
#pragma unroll
        for (int off = 32; off; off >>= 1) ss += __shfl_xor(ss, off, 64);
        float o = fmaxf(acc / fmaxf(sqrtf(ss), 1e-12f), 0.f);
        if (POOL) {
            unsafeAtomicAdd(&pooled[(size_t)batch[nd] * 64 + lane], o);
        } else {
            Q[(size_t)nd * 64 + lane] = o;
        }
    }
}

// ---------------- per-graph MLP + log_softmax ----------------

__global__ void k_mlp(const float* __restrict__ pooled,
                      const float* __restrict__ fc1w, const float* __restrict__ fc1b,
                      const float* __restrict__ fc2w, const float* __restrict__ fc2b,
                      float* __restrict__ out, int G) {
    __shared__ float sp[64];
    __shared__ float sz[64];
    __shared__ float sl[10];
    __shared__ float slse;
    int g = blockIdx.x;
    int t = threadIdx.x;
    if (g >= G) return;
    sp[t] = pooled[(size_t)g * 64 + t];
    __syncthreads();
    float acc = fc1b[t];
#pragma unroll
    for (int k = 0; k < 64; ++k) acc += sp[k] * fc1w[k * 64 + t];
    sz[t] = fmaxf(acc, 0.f);
    __syncthreads();
    if (t < 10) {
        float a = fc2b[t];
#pragma unroll
        for (int j = 0; j < 64; ++j) a += sz[j] * fc2w[j * 10 + t];
        sl[t] = a;
    }
    __syncthreads();
    if (t == 0) {
        float m = sl[0];
        for (int c = 1; c < 10; ++c) m = fmaxf(m, sl[c]);
        float s = 0.f;
        for (int c = 0; c < 10; ++c) s += expf(sl[c] - m);
        slse = m + logf(s);
    }
    __syncthreads();
    if (t < 10) out[(size_t)g * 10 + t] = sl[t] - slse;
}

// ---------------- launch ----------------

extern "C" void kernel_launch(void* const* d_in, const int* in_sizes, int n_in,
                              void* d_out, int out_size, void* d_ws, size_t ws_size,
                              hipStream_t stream) {
    const float* x     = (const float*)d_in[0];
    const int*   ei    = (const int*)d_in[1];
    const int*   batch = (const int*)d_in[2];
    const float* ew    = (const float*)d_in[3];
    const float* W1 = (const float*)d_in[4];
    const float* b1 = (const float*)d_in[5];
    const float* W2 = (const float*)d_in[6];
    const float* b2 = (const float*)d_in[7];
    const float* W3 = (const float*)d_in[8];
    const float* b3 = (const float*)d_in[9];
    const float* fc1w = (const float*)d_in[10];
    const float* fc1b = (const float*)d_in[11];
    const float* fc2w = (const float*)d_in[12];
    const float* fc2b = (const float*)d_in[13];
    float* out = (float*)d_out;

    const int N = in_sizes[0] / 128;   // 100000
    const int E = in_sizes[1] / 2;     // 3200000
    const int G = out_size / 10;       // 512

    // workspace layout
    float* P       = (float*)d_ws;                    // N*64 f32
    float* Q       = P + (size_t)N * 64;              // N*64 f32
    float* dinv    = Q + (size_t)N * 64;              // N f32
    float* pooled  = dinv + N;                        // G*64 f32
    int*   cnt     = (int*)(pooled + (size_t)G * 64); // N int
    int*   row_ptr = cnt + N;                         // N+1 int
    int*   cursor  = row_ptr + (N + 1);               // N int
    int2*  meta    = (int2*)(cursor + N);             // E int2  (align: offset is multiple of 8B from ws start? ensure)
    // (all preceding counts are even except row_ptr N+1; fix alignment)
    {
        size_t off = (size_t)(cursor + N - (int*)d_ws);
        if (off & 1) meta = (int2*)((int*)d_ws + off + 1);
    }

    dim3 blk(256);
    dim3 g2048(2048);

    // degree + histogram -> dinv, row_ptr, cursor
    k_fill_f<<<dim3(512), blk, 0, stream>>>(dinv, 1.0f, N);
    k_fill_i<<<dim3(512), blk, 0, stream>>>(cnt, 0, N);
    k_deg_hist<<<g2048, blk, 0, stream>>>(ei, ew, dinv, cnt, E);
    k_inv_sqrt<<<dim3(512), blk, 0, stream>>>(dinv, N);
    k_scan<<<dim3(1), dim3(1024), 0, stream>>>(cnt, row_ptr, cursor, N);
    k_fill_edges<<<g2048, blk, 0, stream>>>(ei, ew, dinv, cursor, meta, E);

    // conv1 (K=128)
    k_gemm<128><<<g2048, blk, 0, stream>>>(x, W1, P, N);
    k_conv<false><<<g2048, blk, 0, stream>>>(P, row_ptr, meta, dinv, b1, batch, Q, nullptr, N);

    // conv2
    k_gemm<64><<<g2048, blk, 0, stream>>>(Q, W2, P, N);
    k_conv<false><<<g2048, blk, 0, stream>>>(P, row_ptr, meta, dinv, b2, batch, Q, nullptr, N);

    // conv3 + fused pool (per-node output is discarded after pooling)
    k_gemm<64><<<g2048, blk, 0, stream>>>(Q, W3, P, N);
    k_fill_f<<<dim3(64), blk, 0, stream>>>(pooled, 0.0f, G * 64);
    k_conv<true><<<g2048, blk, 0, stream>>>(P, row_ptr, meta, dinv, b3, batch, nullptr, pooled, N);

    // MLP + log_softmax
    k_mlp<<<dim3(G), dim3(64), 0, stream>>>(pooled, fc1w, fc1b, fc2w, fc2b, out, G);
}

// Round 3
// 876.789 us; speedup vs baseline: 2.8452x; 1.4581x over previous
//
#include <hip/hip_runtime.h>
#include <hip/hip_bf16.h>
#include <math.h>

typedef __hip_bfloat16 bf16;

// ---------------- fills ----------------

__global__ void k_fill_i(int* __restrict__ p, int v, int n) {
    int i = blockIdx.x * blockDim.x + threadIdx.x;
    int s = gridDim.x * blockDim.x;
    for (; i < n; i += s) p[i] = v;
}

// ---------------- CSR build ----------------
// lp[e] = old count of dst  (the ONLY atomic pass: 3.2M atomics)
__global__ void k_hist_pos(const int* __restrict__ ei, int* __restrict__ cnt,
                           int* __restrict__ lp, int E) {
    int i = blockIdx.x * blockDim.x + threadIdx.x;
    int s = gridDim.x * blockDim.x;
    for (; i < E; i += s) lp[i] = atomicAdd(&cnt[ei[E + i]], 1);
}

// 3-phase exclusive scan of cnt[N] -> row_ptr[N+1], chunk = 512/block
__global__ void k_scan_a(const int* __restrict__ cnt, int* __restrict__ bsum, int n) {
    __shared__ int red[256];
    int t = threadIdx.x;
    int base = blockIdx.x * 512;
    int s = 0;
    for (int i = base + t; i < base + 512; i += 256) s += (i < n) ? cnt[i] : 0;
    red[t] = s;
    __syncthreads();
    for (int off = 128; off; off >>= 1) {
        if (t < off) red[t] += red[t + off];
        __syncthreads();
    }
    if (t == 0) bsum[blockIdx.x] = red[0];
}

__global__ void k_scan_b(int* __restrict__ bsum, int nb) {  // nb <= 256
    __shared__ int v[256];
    int t = threadIdx.x;
    v[t] = (t < nb) ? bsum[t] : 0;
    __syncthreads();
    for (int off = 1; off < 256; off <<= 1) {
        int add = (t >= off) ? v[t - off] : 0;
        __syncthreads();
        v[t] += add;
        __syncthreads();
    }
    int excl = (t == 0) ? 0 : v[t - 1];
    if (t < nb) bsum[t] = excl;
}

__global__ void k_scan_c(const int* __restrict__ cnt, const int* __restrict__ bsum,
                         int* __restrict__ row_ptr, int n) {
    __shared__ int ts[256];
    int t = threadIdx.x;
    int base = blockIdx.x * 512;
    int i0 = base + 2 * t;
    int c0 = (i0 < n) ? cnt[i0] : 0;
    int c1 = (i0 + 1 < n) ? cnt[i0 + 1] : 0;
    ts[t] = c0 + c1;
    __syncthreads();
    for (int off = 1; off < 256; off <<= 1) {
        int add = (t >= off) ? ts[t - off] : 0;
        __syncthreads();
        ts[t] += add;
        __syncthreads();
    }
    int pre = bsum[blockIdx.x] + ((t == 0) ? 0 : ts[t - 1]);
    if (i0 < n) row_ptr[i0] = pre;
    if (i0 + 1 < n) row_ptr[i0 + 1] = pre + c0;
    if (i0 == n - 1) row_ptr[n] = pre + c0;
    else if (i0 + 1 == n - 1) row_ptr[n] = pre + c0 + c1;
}

// meta[row_ptr[dst]+lp[e]] = (src, ew)  -- no atomics
__global__ void k_fill2(const int* __restrict__ ei, const float* __restrict__ ew,
                        const int* __restrict__ row_ptr, const int* __restrict__ lp,
                        int2* __restrict__ meta, int E) {
    int i = blockIdx.x * blockDim.x + threadIdx.x;
    int s = gridDim.x * blockDim.x;
    for (; i < E; i += s) {
        int dst = ei[E + i];
        meta[row_ptr[dst] + lp[i]] = make_int2(ei[i], __float_as_int(ew[i]));
    }
}

// dinv[n] = rsqrt(1 + sum ew over row)  -- gather, no atomics
__global__ void k_deg(const int2* __restrict__ meta, const int* __restrict__ row_ptr,
                      float* __restrict__ dinv, int N) {
    int i = blockIdx.x * blockDim.x + threadIdx.x;
    int s = gridDim.x * blockDim.x;
    for (; i < N; i += s) {
        float d = 1.0f;
        int e1 = row_ptr[i + 1];
        for (int e = row_ptr[i]; e < e1; ++e) d += __int_as_float(meta[e].y);
        dinv[i] = rsqrtf(d);
    }
}

// meta.y: ew -> dinv[src]*ew*dinv[dst]
__global__ void k_norm(int2* __restrict__ meta, const int* __restrict__ row_ptr,
                       const float* __restrict__ dinv, int N) {
    int i = blockIdx.x * blockDim.x + threadIdx.x;
    int s = gridDim.x * blockDim.x;
    for (; i < N; i += s) {
        float dn = dinv[i];
        int e1 = row_ptr[i + 1];
        for (int e = row_ptr[i]; e < e1; ++e) {
            int2 m = meta[e];
            meta[e].y = __float_as_int(dinv[m.x] * __int_as_float(m.y) * dn);
        }
    }
}

// ---------------- dense H@W (W in LDS), bf16 output ----------------

template <int K>
__global__ void k_gemm(const float* __restrict__ X, const float* __restrict__ W,
                       bf16* __restrict__ out, int n_nodes) {
    __shared__ float sW[K * 64];
    for (int i = threadIdx.x; i < K * 64; i += blockDim.x) sW[i] = W[i];
    __syncthreads();
    int f = threadIdx.x & 63;
    int local = threadIdx.x >> 6;
    int nper = blockDim.x >> 6;
    for (int node = blockIdx.x * nper + local; node < n_nodes; node += gridDim.x * nper) {
        const float* xr = X + (size_t)node * K;
        float acc = 0.f;
#pragma unroll 8
        for (int k = 0; k < K; ++k) acc += xr[k] * sW[k * 64 + f];
        out[(size_t)node * 64 + f] = __float2bfloat16(acc);
    }
}

// ---------------- fused gather-conv + bias + l2norm + relu ----------------

__global__ void k_conv(const bf16* __restrict__ P, const int* __restrict__ row_ptr,
                       const int2* __restrict__ meta, const float* __restrict__ dinv,
                       const float* __restrict__ b, float* __restrict__ Q, int n_nodes) {
    int lane = threadIdx.x & 63;
    int w = blockIdx.x * (blockDim.x >> 6) + (threadIdx.x >> 6);
    int nw = gridDim.x * (blockDim.x >> 6);
    for (int nd = w; nd < n_nodes; nd += nw) {
        float d = dinv[nd];
        float acc = d * d * __bfloat162float(P[(size_t)nd * 64 + lane]);
        int e = row_ptr[nd], end = row_ptr[nd + 1];
        for (; e + 3 < end; e += 4) {
            int2 m0 = meta[e], m1 = meta[e + 1], m2 = meta[e + 2], m3 = meta[e + 3];
            float p0 = __bfloat162float(P[(size_t)m0.x * 64 + lane]);
            float p1 = __bfloat162float(P[(size_t)m1.x * 64 + lane]);
            float p2 = __bfloat162float(P[(size_t)m2.x * 64 + lane]);
            float p3 = __bfloat162float(P[(size_t)m3.x * 64 + lane]);
            acc = fmaf(__int_as_float(m0.y), p0, acc);
            acc = fmaf(__int_as_float(m1.y), p1, acc);
            acc = fmaf(__int_as_float(m2.y), p2, acc);
            acc = fmaf(__int_as_float(m3.y), p3, acc);
        }
        for (; e < end; ++e) {
            int2 m = meta[e];
            acc = fmaf(__int_as_float(m.y), __bfloat162float(P[(size_t)m.x * 64 + lane]), acc);
        }
        acc += b[lane];
        float ss = acc * acc;
#pragma unroll
        for (int off = 32; off; off >>= 1) ss += __shfl_xor(ss, off, 64);
        float o = fmaxf(acc / fmaxf(sqrtf(ss), 1e-12f), 0.f);
        Q[(size_t)nd * 64 + lane] = o;
    }
}

// ---------------- segmented pool (batch sorted) ----------------

__global__ void k_starts(const int* __restrict__ batch, int* __restrict__ starts,
                         int N, int G) {
    int g = blockIdx.x * blockDim.x + threadIdx.x;
    if (g > G) return;
    int lo = 0, hi = N;
    while (lo < hi) {
        int mid = (lo + hi) >> 1;
        if (batch[mid] < g) lo = mid + 1; else hi = mid;
    }
    starts[g] = lo;
}

__global__ void k_pool(const float* __restrict__ Q, const int* __restrict__ starts,
                       float* __restrict__ pooled, int G) {
    int lane = threadIdx.x & 63;
    int w = blockIdx.x * (blockDim.x >> 6) + (threadIdx.x >> 6);
    if (w >= G) return;
    float acc = 0.f;
    int end = starts[w + 1];
    for (int i = starts[w]; i < end; ++i) acc += Q[(size_t)i * 64 + lane];
    pooled[(size_t)w * 64 + lane] = acc;
}

// ---------------- per-graph MLP + log_softmax ----------------

__global__ void k_mlp(const float* __restrict__ pooled,
                      const float* __restrict__ fc1w, const float* __restrict__ fc1b,
                      const float* __restrict__ fc2w, const float* __restrict__ fc2b,
                      float* __restrict__ out, int G) {
    __shared__ float sp[64];
    __shared__ float sz[64];
    __shared__ float sl[10];
    __shared__ float slse;
    int g = blockIdx.x;
    int t = threadIdx.x;
    if (g >= G) return;
    sp[t] = pooled[(size_t)g * 64 + t];
    __syncthreads();
    float acc = fc1b[t];
#pragma unroll
    for (int k = 0; k < 64; ++k) acc += sp[k] * fc1w[k * 64 + t];
    sz[t] = fmaxf(acc, 0.f);
    __syncthreads();
    if (t < 10) {
        float a = fc2b[t];
#pragma unroll
        for (int j = 0; j < 64; ++j) a += sz[j] * fc2w[j * 10 + t];
        sl[t] = a;
    }
    __syncthreads();
    if (t == 0) {
        float m = sl[0];
        for (int c = 1; c < 10; ++c) m = fmaxf(m, sl[c]);
        float s = 0.f;
        for (int c = 0; c < 10; ++c) s += expf(sl[c] - m);
        slse = m + logf(s);
    }
    __syncthreads();
    if (t < 10) out[(size_t)g * 10 + t] = sl[t] - slse;
}

// ---------------- launch ----------------

extern "C" void kernel_launch(void* const* d_in, const int* in_sizes, int n_in,
                              void* d_out, int out_size, void* d_ws, size_t ws_size,
                              hipStream_t stream) {
    const float* x     = (const float*)d_in[0];
    const int*   ei    = (const int*)d_in[1];
    const int*   batch = (const int*)d_in[2];
    const float* ew    = (const float*)d_in[3];
    const float* W1 = (const float*)d_in[4];
    const float* b1 = (const float*)d_in[5];
    const float* W2 = (const float*)d_in[6];
    const float* b2 = (const float*)d_in[7];
    const float* W3 = (const float*)d_in[8];
    const float* b3 = (const float*)d_in[9];
    const float* fc1w = (const float*)d_in[10];
    const float* fc1b = (const float*)d_in[11];
    const float* fc2w = (const float*)d_in[12];
    const float* fc2b = (const float*)d_in[13];
    float* out = (float*)d_out;

    const int N = in_sizes[0] / 128;   // 100000
    const int E = in_sizes[1] / 2;     // 3200000
    const int G = out_size / 10;       // 512

    // workspace (256B-aligned chunks)
    char* wp = (char*)d_ws;
    auto alloc = [&](size_t bytes) {
        char* p = wp;
        wp += (bytes + 255) & ~(size_t)255;
        return p;
    };
    float* Q       = (float*)alloc((size_t)N * 64 * 4);
    bf16*  P       = (bf16*) alloc((size_t)N * 64 * 2);
    int2*  meta    = (int2*) alloc((size_t)E * 8);
    int*   lp      = (int*)  alloc((size_t)E * 4);
    int*   cnt     = (int*)  alloc((size_t)N * 4);
    int*   row_ptr = (int*)  alloc((size_t)(N + 1) * 4);
    float* dinv    = (float*)alloc((size_t)N * 4);
    float* pooled  = (float*)alloc((size_t)G * 64 * 4);
    int*   starts  = (int*)  alloc((size_t)(G + 1) * 4);
    int*   bsum    = (int*)  alloc(4096);

    dim3 blk(256);
    dim3 g2048(2048);
    const int NBLK_SCAN = (N + 511) / 512;           // 196 (<=256)
    const int NBLK_NODE = (N + 255) / 256;

    // CSR build (single atomic pass)
    k_fill_i<<<dim3(256), blk, 0, stream>>>(cnt, 0, N);
    k_hist_pos<<<g2048, blk, 0, stream>>>(ei, cnt, lp, E);
    k_scan_a<<<dim3(NBLK_SCAN), blk, 0, stream>>>(cnt, bsum, N);
    k_scan_b<<<dim3(1), blk, 0, stream>>>(bsum, NBLK_SCAN);
    k_scan_c<<<dim3(NBLK_SCAN), blk, 0, stream>>>(cnt, bsum, row_ptr, N);
    k_fill2<<<g2048, blk, 0, stream>>>(ei, ew, row_ptr, lp, meta, E);
    k_deg<<<dim3(NBLK_NODE), blk, 0, stream>>>(meta, row_ptr, dinv, N);
    k_norm<<<dim3(NBLK_NODE), blk, 0, stream>>>(meta, row_ptr, dinv, N);
    k_starts<<<dim3((G + 256) / 256 + 1), blk, 0, stream>>>(batch, starts, N, G);

    // conv1 (K=128)
    k_gemm<128><<<g2048, blk, 0, stream>>>(x, W1, P, N);
    k_conv<<<g2048, blk, 0, stream>>>(P, row_ptr, meta, dinv, b1, Q, N);
    // conv2
    k_gemm<64><<<g2048, blk, 0, stream>>>(Q, W2, P, N);
    k_conv<<<g2048, blk, 0, stream>>>(P, row_ptr, meta, dinv, b2, Q, N);
    // conv3
    k_gemm<64><<<g2048, blk, 0, stream>>>(Q, W3, P, N);
    k_conv<<<g2048, blk, 0, stream>>>(P, row_ptr, meta, dinv, b3, Q, N);

    // pool + MLP
    k_pool<<<dim3((G * 64 + 255) / 256), blk, 0, stream>>>(Q, starts, pooled, G);
    k_mlp<<<dim3(G), dim3(64), 0, stream>>>(pooled, fc1w, fc1b, fc2w, fc2b, out, G);
}

// Round 4
// 737.501 us; speedup vs baseline: 3.3826x; 1.1889x over previous
//
#include <hip/hip_runtime.h>
#include <math.h>

typedef __bf16 bf16_t;
typedef __attribute__((ext_vector_type(8))) __bf16 bf16x8;
typedef __attribute__((ext_vector_type(4))) float f32x4;

// ---------------- fills ----------------

__global__ void k_fill_i(int* __restrict__ p, int v, int n) {
    int i = blockIdx.x * blockDim.x + threadIdx.x;
    int s = gridDim.x * blockDim.x;
    for (; i < n; i += s) p[i] = v;
}

// ---------------- CSR build ----------------
// lp[e] = old count of dst  (the ONLY atomic pass: 3.2M atomics)
__global__ void k_hist_pos(const int* __restrict__ ei, int* __restrict__ cnt,
                           int* __restrict__ lp, int E) {
    int i = blockIdx.x * blockDim.x + threadIdx.x;
    int s = gridDim.x * blockDim.x;
    for (; i < E; i += s) lp[i] = atomicAdd(&cnt[ei[E + i]], 1);
}

// 3-phase exclusive scan of cnt[N] -> row_ptr[N+1], chunk = 512/block
__global__ void k_scan_a(const int* __restrict__ cnt, int* __restrict__ bsum, int n) {
    __shared__ int red[256];
    int t = threadIdx.x;
    int base = blockIdx.x * 512;
    int s = 0;
    for (int i = base + t; i < base + 512; i += 256) s += (i < n) ? cnt[i] : 0;
    red[t] = s;
    __syncthreads();
    for (int off = 128; off; off >>= 1) {
        if (t < off) red[t] += red[t + off];
        __syncthreads();
    }
    if (t == 0) bsum[blockIdx.x] = red[0];
}

__global__ void k_scan_b(int* __restrict__ bsum, int nb) {  // nb <= 256
    __shared__ int v[256];
    int t = threadIdx.x;
    v[t] = (t < nb) ? bsum[t] : 0;
    __syncthreads();
    for (int off = 1; off < 256; off <<= 1) {
        int add = (t >= off) ? v[t - off] : 0;
        __syncthreads();
        v[t] += add;
        __syncthreads();
    }
    int excl = (t == 0) ? 0 : v[t - 1];
    if (t < nb) bsum[t] = excl;
}

__global__ void k_scan_c(const int* __restrict__ cnt, const int* __restrict__ bsum,
                         int* __restrict__ row_ptr, int n) {
    __shared__ int ts[256];
    int t = threadIdx.x;
    int base = blockIdx.x * 512;
    int i0 = base + 2 * t;
    int c0 = (i0 < n) ? cnt[i0] : 0;
    int c1 = (i0 + 1 < n) ? cnt[i0 + 1] : 0;
    ts[t] = c0 + c1;
    __syncthreads();
    for (int off = 1; off < 256; off <<= 1) {
        int add = (t >= off) ? ts[t - off] : 0;
        __syncthreads();
        ts[t] += add;
        __syncthreads();
    }
    int pre = bsum[blockIdx.x] + ((t == 0) ? 0 : ts[t - 1]);
    if (i0 < n) row_ptr[i0] = pre;
    if (i0 + 1 < n) row_ptr[i0 + 1] = pre + c0;
    if (i0 == n - 1) row_ptr[n] = pre + c0;
    else if (i0 + 1 == n - 1) row_ptr[n] = pre + c0 + c1;
}

// meta[row_ptr[dst]+lp[e]] = (src, ew)  -- no atomics
__global__ void k_fill2(const int* __restrict__ ei, const float* __restrict__ ew,
                        const int* __restrict__ row_ptr, const int* __restrict__ lp,
                        int2* __restrict__ meta, int E) {
    int i = blockIdx.x * blockDim.x + threadIdx.x;
    int s = gridDim.x * blockDim.x;
    for (; i < E; i += s) {
        int dst = ei[E + i];
        meta[row_ptr[dst] + lp[i]] = make_int2(ei[i], __float_as_int(ew[i]));
    }
}

// dinv[n] = rsqrt(1 + sum ew over row)
__global__ void k_deg(const int2* __restrict__ meta, const int* __restrict__ row_ptr,
                      float* __restrict__ dinv, int N) {
    int i = blockIdx.x * blockDim.x + threadIdx.x;
    int s = gridDim.x * blockDim.x;
    for (; i < N; i += s) {
        float d = 1.0f;
        int e1 = row_ptr[i + 1];
        for (int e = row_ptr[i]; e < e1; ++e) d += __int_as_float(meta[e].y);
        dinv[i] = rsqrtf(d);
    }
}

// meta.y: ew -> dinv[src]*ew*dinv[dst]
__global__ void k_norm(int2* __restrict__ meta, const int* __restrict__ row_ptr,
                       const float* __restrict__ dinv, int N) {
    int i = blockIdx.x * blockDim.x + threadIdx.x;
    int s = gridDim.x * blockDim.x;
    for (; i < N; i += s) {
        float dn = dinv[i];
        int e1 = row_ptr[i + 1];
        for (int e = row_ptr[i]; e < e1; ++e) {
            int2 m = meta[e];
            meta[e].y = __float_as_int(dinv[m.x] * __int_as_float(m.y) * dn);
        }
    }
}

// ---------------- MFMA GEMM: out[n][f] = X[n][:] @ W[:][f] ----------------
// mfma_f32_16x16x32_bf16 layout (gfx950, ref-verified m91/m97):
//   A: row=lane&15, k=(lane>>4)*8+j (contiguous 8)
//   B: col=lane&15, k=(lane>>4)*8+j
//   C/D: col=lane&15, row=(lane>>4)*4+reg
// 4 waves/block, wave w owns cols [16w,16w+16); N assumed multiple of 16.

template <int K, bool A_F32, bool OUT_BF16>
__global__ __launch_bounds__(256) void k_gemm_mfma(
        const void* __restrict__ Xv, const float* __restrict__ W,
        bf16_t* __restrict__ outb, float* __restrict__ outf, int ntiles) {
    __shared__ bf16_t sWt[64 * K];              // transposed W: sWt[c*K + k]
    for (int idx = threadIdx.x; idx < K * 64; idx += blockDim.x) {
        int k = idx >> 6, c = idx & 63;
        sWt[c * K + k] = (bf16_t)W[idx];
    }
    __syncthreads();

    int lane = threadIdx.x & 63;
    int wid  = threadIdx.x >> 6;
    int colbase = wid * 16;
    int lm = lane & 15;
    int lk = lane >> 4;

    bf16x8 bfrag[K / 32];
#pragma unroll
    for (int ks = 0; ks < K / 32; ++ks)
        bfrag[ks] = *(const bf16x8*)&sWt[(colbase + lm) * K + ks * 32 + lk * 8];

    const float*  Xf = (const float*)Xv;
    const bf16_t* Xb = (const bf16_t*)Xv;

    for (int t = blockIdx.x; t < ntiles; t += gridDim.x) {
        f32x4 acc = {0.f, 0.f, 0.f, 0.f};
        size_t rowoff = (size_t)(t * 16 + lm) * K + lk * 8;
#pragma unroll
        for (int ks = 0; ks < K / 32; ++ks) {
            bf16x8 afrag;
            if (A_F32) {
                float4 v0 = *(const float4*)(Xf + rowoff + ks * 32);
                float4 v1 = *(const float4*)(Xf + rowoff + ks * 32 + 4);
                afrag[0] = (bf16_t)v0.x; afrag[1] = (bf16_t)v0.y;
                afrag[2] = (bf16_t)v0.z; afrag[3] = (bf16_t)v0.w;
                afrag[4] = (bf16_t)v1.x; afrag[5] = (bf16_t)v1.y;
                afrag[6] = (bf16_t)v1.z; afrag[7] = (bf16_t)v1.w;
            } else {
                afrag = *(const bf16x8*)(Xb + rowoff + ks * 32);
            }
            acc = __builtin_amdgcn_mfma_f32_16x16x32_bf16(afrag, bfrag[ks], acc, 0, 0, 0);
        }
#pragma unroll
        for (int r = 0; r < 4; ++r) {
            int row = t * 16 + lk * 4 + r;
            size_t oi = (size_t)row * 64 + colbase + lm;
            if (OUT_BF16) outb[oi] = (bf16_t)acc[r];
            else          outf[oi] = acc[r];
        }
    }
}

// ---------------- fused gather-conv + bias + l2norm + relu ----------------

template <typename OT>
__global__ void k_conv(const bf16_t* __restrict__ P, const int* __restrict__ row_ptr,
                       const int2* __restrict__ meta, const float* __restrict__ dinv,
                       const float* __restrict__ b, OT* __restrict__ Q, int n_nodes) {
    int lane = threadIdx.x & 63;
    int w = blockIdx.x * (blockDim.x >> 6) + (threadIdx.x >> 6);
    int nw = gridDim.x * (blockDim.x >> 6);
    for (int nd = w; nd < n_nodes; nd += nw) {
        float d = dinv[nd];
        float acc = d * d * (float)P[(size_t)nd * 64 + lane];
        int e = row_ptr[nd], end = row_ptr[nd + 1];
        for (; e + 3 < end; e += 4) {
            int2 m0 = meta[e], m1 = meta[e + 1], m2 = meta[e + 2], m3 = meta[e + 3];
            float p0 = (float)P[(size_t)m0.x * 64 + lane];
            float p1 = (float)P[(size_t)m1.x * 64 + lane];
            float p2 = (float)P[(size_t)m2.x * 64 + lane];
            float p3 = (float)P[(size_t)m3.x * 64 + lane];
            acc = fmaf(__int_as_float(m0.y), p0, acc);
            acc = fmaf(__int_as_float(m1.y), p1, acc);
            acc = fmaf(__int_as_float(m2.y), p2, acc);
            acc = fmaf(__int_as_float(m3.y), p3, acc);
        }
        for (; e < end; ++e) {
            int2 m = meta[e];
            acc = fmaf(__int_as_float(m.y), (float)P[(size_t)m.x * 64 + lane], acc);
        }
        acc += b[lane];
        float ss = acc * acc;
#pragma unroll
        for (int off = 32; off; off >>= 1) ss += __shfl_xor(ss, off, 64);
        float o = fmaxf(acc / fmaxf(sqrtf(ss), 1e-12f), 0.f);
        Q[(size_t)nd * 64 + lane] = (OT)o;
    }
}

// ---------------- segmented pool (batch sorted) ----------------

__global__ void k_starts(const int* __restrict__ batch, int* __restrict__ starts,
                         int N, int G) {
    int g = blockIdx.x * blockDim.x + threadIdx.x;
    if (g > G) return;
    int lo = 0, hi = N;
    while (lo < hi) {
        int mid = (lo + hi) >> 1;
        if (batch[mid] < g) lo = mid + 1; else hi = mid;
    }
    starts[g] = lo;
}

__global__ void k_pool(const float* __restrict__ Q, const int* __restrict__ starts,
                       float* __restrict__ pooled, int G) {
    int lane = threadIdx.x & 63;
    int w = blockIdx.x * (blockDim.x >> 6) + (threadIdx.x >> 6);
    if (w >= G) return;
    float acc = 0.f;
    int end = starts[w + 1];
    for (int i = starts[w]; i < end; ++i) acc += Q[(size_t)i * 64 + lane];
    pooled[(size_t)w * 64 + lane] = acc;
}

// ---------------- per-graph MLP + log_softmax ----------------

__global__ void k_mlp(const float* __restrict__ pooled,
                      const float* __restrict__ fc1w, const float* __restrict__ fc1b,
                      const float* __restrict__ fc2w, const float* __restrict__ fc2b,
                      float* __restrict__ out, int G) {
    __shared__ float sp[64];
    __shared__ float sz[64];
    __shared__ float sl[10];
    __shared__ float slse;
    int g = blockIdx.x;
    int t = threadIdx.x;
    if (g >= G) return;
    sp[t] = pooled[(size_t)g * 64 + t];
    __syncthreads();
    float acc = fc1b[t];
#pragma unroll
    for (int k = 0; k < 64; ++k) acc += sp[k] * fc1w[k * 64 + t];
    sz[t] = fmaxf(acc, 0.f);
    __syncthreads();
    if (t < 10) {
        float a = fc2b[t];
#pragma unroll
        for (int j = 0; j < 64; ++j) a += sz[j] * fc2w[j * 10 + t];
        sl[t] = a;
    }
    __syncthreads();
    if (t == 0) {
        float m = sl[0];
        for (int c = 1; c < 10; ++c) m = fmaxf(m, sl[c]);
        float s = 0.f;
        for (int c = 0; c < 10; ++c) s += expf(sl[c] - m);
        slse = m + logf(s);
    }
    __syncthreads();
    if (t < 10) out[(size_t)g * 10 + t] = sl[t] - slse;
}

// ---------------- launch ----------------

extern "C" void kernel_launch(void* const* d_in, const int* in_sizes, int n_in,
                              void* d_out, int out_size, void* d_ws, size_t ws_size,
                              hipStream_t stream) {
    const float* x     = (const float*)d_in[0];
    const int*   ei    = (const int*)d_in[1];
    const int*   batch = (const int*)d_in[2];
    const float* ew    = (const float*)d_in[3];
    const float* W1 = (const float*)d_in[4];
    const float* b1 = (const float*)d_in[5];
    const float* W2 = (const float*)d_in[6];
    const float* b2 = (const float*)d_in[7];
    const float* W3 = (const float*)d_in[8];
    const float* b3 = (const float*)d_in[9];
    const float* fc1w = (const float*)d_in[10];
    const float* fc1b = (const float*)d_in[11];
    const float* fc2w = (const float*)d_in[12];
    const float* fc2b = (const float*)d_in[13];
    float* out = (float*)d_out;

    const int N = in_sizes[0] / 128;   // 100000 (multiple of 16)
    const int E = in_sizes[1] / 2;     // 3200000
    const int G = out_size / 10;       // 512

    // workspace (256B-aligned chunks)
    char* wp = (char*)d_ws;
    auto alloc = [&](size_t bytes) {
        char* p = wp;
        wp += (bytes + 255) & ~(size_t)255;
        return p;
    };
    float*  Qf      = (float*)alloc((size_t)N * 64 * 4);  // f32 view (conv3 out, pool in)
    bf16_t* Qb      = (bf16_t*)Qf;                        // bf16 view (conv1/2 out, gemm in)
    bf16_t* P       = (bf16_t*)alloc((size_t)N * 64 * 2);
    int2*   meta    = (int2*) alloc((size_t)E * 8);
    int*    lp      = (int*)  alloc((size_t)E * 4);
    int*    cnt     = (int*)  alloc((size_t)N * 4);
    int*    row_ptr = (int*)  alloc((size_t)(N + 1) * 4);
    float*  dinv    = (float*)alloc((size_t)N * 4);
    float*  pooled  = (float*)alloc((size_t)G * 64 * 4);
    int*    starts  = (int*)  alloc((size_t)(G + 1) * 4);
    int*    bsum    = (int*)  alloc(4096);

    dim3 blk(256);
    dim3 g2048(2048);
    dim3 g1024(1024);
    const int NBLK_SCAN = (N + 511) / 512;           // 196 (<=256)
    const int NBLK_NODE = (N + 255) / 256;
    const int ntiles = N / 16;                       // 6250

    // CSR build (single atomic pass)
    k_fill_i<<<dim3(256), blk, 0, stream>>>(cnt, 0, N);
    k_hist_pos<<<g2048, blk, 0, stream>>>(ei, cnt, lp, E);
    k_scan_a<<<dim3(NBLK_SCAN), blk, 0, stream>>>(cnt, bsum, N);
    k_scan_b<<<dim3(1), blk, 0, stream>>>(bsum, NBLK_SCAN);
    k_scan_c<<<dim3(NBLK_SCAN), blk, 0, stream>>>(cnt, bsum, row_ptr, N);
    k_fill2<<<g2048, blk, 0, stream>>>(ei, ew, row_ptr, lp, meta, E);
    k_deg<<<dim3(NBLK_NODE), blk, 0, stream>>>(meta, row_ptr, dinv, N);
    k_norm<<<dim3(NBLK_NODE), blk, 0, stream>>>(meta, row_ptr, dinv, N);
    k_starts<<<dim3((G + 256) / 256 + 1), blk, 0, stream>>>(batch, starts, N, G);

    // conv1 (K=128, f32 A with in-register bf16 convert)
    k_gemm_mfma<128, true, true><<<g1024, blk, 0, stream>>>(x, W1, P, nullptr, ntiles);
    k_conv<bf16_t><<<g2048, blk, 0, stream>>>(P, row_ptr, meta, dinv, b1, Qb, N);
    // conv2 (K=64, bf16 A)
    k_gemm_mfma<64, false, true><<<g1024, blk, 0, stream>>>(Qb, W2, P, nullptr, ntiles);
    k_conv<bf16_t><<<g2048, blk, 0, stream>>>(P, row_ptr, meta, dinv, b2, Qb, N);
    // conv3 (K=64, bf16 A, f32 node output for pooling)
    k_gemm_mfma<64, false, true><<<g1024, blk, 0, stream>>>(Qb, W3, P, nullptr, ntiles);
    k_conv<float><<<g2048, blk, 0, stream>>>(P, row_ptr, meta, dinv, b3, Qf, N);

    // pool + MLP
    k_pool<<<dim3((G * 64 + 255) / 256), blk, 0, stream>>>(Qf, starts, pooled, G);
    k_mlp<<<dim3(G), dim3(64), 0, stream>>>(pooled, fc1w, fc1b, fc2w, fc2b, out, G);
}

// Round 5
// 619.311 us; speedup vs baseline: 4.0281x; 1.1908x over previous
//
#include <hip/hip_runtime.h>
#include <math.h>

typedef __bf16 bf16_t;
typedef __attribute__((ext_vector_type(8))) __bf16 bf16x8;
typedef __attribute__((ext_vector_type(4))) float f32x4;

#define BTILE 16384

// ---------------- fills ----------------

__global__ void k_fill_i(int* __restrict__ p, int v, int n) {
    int i = blockIdx.x * blockDim.x + threadIdx.x;
    int s = gridDim.x * blockDim.x;
    for (; i < n; i += s) p[i] = v;
}

// ---------------- Pass A: bucket histogram (bucket = dst>>7) ----------------

__global__ void k_bucket_hist(const int* __restrict__ dstp, int E, int NB,
                              int* __restrict__ btot) {
    __shared__ int lh[1024];
    for (int i = threadIdx.x; i < 1024; i += blockDim.x) lh[i] = 0;
    __syncthreads();
    int i = blockIdx.x * blockDim.x + threadIdx.x;
    int s = gridDim.x * blockDim.x;
    for (; i < E; i += s) atomicAdd(&lh[dstp[i] >> 7], 1);
    __syncthreads();
    for (int b = threadIdx.x; b < NB; b += blockDim.x) {
        int c = lh[b];
        if (c) atomicAdd(&btot[b], c);
    }
}

// ---------------- bucket scan: btot -> bstart[NB+1], zero bcur ----------------

__global__ void k_bucket_scan(const int* __restrict__ btot, int* __restrict__ bstart,
                              int* __restrict__ bcur, int NB) {
    __shared__ int v[1024];
    int t = threadIdx.x;
    int orig = (t < NB) ? btot[t] : 0;
    v[t] = orig;
    __syncthreads();
    for (int off = 1; off < 1024; off <<= 1) {
        int add = (t >= off) ? v[t - off] : 0;
        __syncthreads();
        v[t] += add;
        __syncthreads();
    }
    if (t < NB) { bstart[t] = v[t] - orig; bcur[t] = 0; }
    if (t == NB - 1) bstart[NB] = v[t];
}

// ---------------- Pass B: bin records into bucket regions ----------------
// record.x = (dst&127)<<17 | src  (src < 131072), record.y = ew bits

__global__ __launch_bounds__(256) void k_passB(const int* __restrict__ ei,
        const float* __restrict__ ew, const int* __restrict__ bstart,
        int* __restrict__ bcur, int2* __restrict__ rec_out, int E, int NB) {
    __shared__ int lhist[1024];
    __shared__ int base[1024];
    __shared__ unsigned short lrank[BTILE];
    const int* dstp = ei + E;
    int tile0 = blockIdx.x * BTILE;
    for (int i = threadIdx.x; i < 1024; i += 256) lhist[i] = 0;
    __syncthreads();
#pragma unroll 4
    for (int j = 0; j < BTILE / 256; ++j) {
        int idx = j * 256 + threadIdx.x;
        int e = tile0 + idx;
        if (e < E) {
            int b = dstp[e] >> 7;
            lrank[idx] = (unsigned short)atomicAdd(&lhist[b], 1);
        }
    }
    __syncthreads();
    for (int b = threadIdx.x; b < NB; b += 256) {
        int c = lhist[b];
        if (c) base[b] = bstart[b] + atomicAdd(&bcur[b], c);
    }
    __syncthreads();
#pragma unroll 4
    for (int j = 0; j < BTILE / 256; ++j) {
        int idx = j * 256 + threadIdx.x;
        int e = tile0 + idx;
        if (e < E) {
            int d = dstp[e];
            int b = d >> 7;
            rec_out[base[b] + lrank[idx]] =
                make_int2(((d & 127) << 17) | ei[e], __float_as_int(ew[e]));
        }
    }
}

// ---------------- Pass C: per-bucket counting sort -> meta, row_ptr, dinv ----------------

__global__ __launch_bounds__(256) void k_passC(const int2* __restrict__ rec_in,
        const int* __restrict__ bstart, int* __restrict__ row_ptr,
        float* __restrict__ dinv, int2* __restrict__ meta, int N, int E) {
    __shared__ int nh[128];
    __shared__ float sw[128];
    __shared__ int offs[128];
    __shared__ int cur[128];
    int b = blockIdx.x, t = threadIdx.x;
    int rs = bstart[b], re = bstart[b + 1];
    if (t < 128) { nh[t] = 0; sw[t] = 0.f; cur[t] = 0; }
    __syncthreads();
    for (int i = rs + t; i < re; i += 256) {
        int2 r = rec_in[i];
        int dl = r.x >> 17;
        atomicAdd(&nh[dl], 1);
        atomicAdd(&sw[dl], __int_as_float(r.y));
    }
    __syncthreads();
    if (t == 0) {
        int s = 0;
        for (int k = 0; k < 128; ++k) { offs[k] = s; s += nh[k]; }
    }
    __syncthreads();
    if (t < 128) {
        int node = b * 128 + t;
        if (node < N) {
            row_ptr[node] = rs + offs[t];
            dinv[node] = rsqrtf(1.f + sw[t]);
        }
    }
    if (b == 0 && t == 0) row_ptr[N] = E;
    __syncthreads();
    for (int i = rs + t; i < re; i += 256) {
        int2 r = rec_in[i];
        int dl = r.x >> 17;
        int pos = rs + offs[dl] + atomicAdd(&cur[dl], 1);
        meta[pos] = make_int2(r.x & 0x1FFFF, r.y);
    }
}

// ---------------- MFMA GEMM: out[n][f] = dinv[n] * (X[n][:] @ W[:][f]) ----------------
// mfma_f32_16x16x32_bf16: A row=lane&15, k=(lane>>4)*8+j; B col=lane&15 same k;
// C/D col=lane&15, row=(lane>>4)*4+reg. 4 waves/block; wave owns 16 cols.

template <int K, bool A_F32>
__global__ __launch_bounds__(256) void k_gemm_mfma(
        const void* __restrict__ Xv, const float* __restrict__ W,
        const float* __restrict__ dinv, bf16_t* __restrict__ outb, int ntiles) {
    __shared__ bf16_t sWt[64 * K];              // transposed W: sWt[c*K + k]
    for (int idx = threadIdx.x; idx < K * 64; idx += blockDim.x) {
        int k = idx >> 6, c = idx & 63;
        sWt[c * K + k] = (bf16_t)W[idx];
    }
    __syncthreads();

    int lane = threadIdx.x & 63;
    int wid  = threadIdx.x >> 6;
    int colbase = wid * 16;
    int lm = lane & 15;
    int lk = lane >> 4;

    bf16x8 bfrag[K / 32];
#pragma unroll
    for (int ks = 0; ks < K / 32; ++ks)
        bfrag[ks] = *(const bf16x8*)&sWt[(colbase + lm) * K + ks * 32 + lk * 8];

    const float*  Xf = (const float*)Xv;
    const bf16_t* Xb = (const bf16_t*)Xv;

    for (int t = blockIdx.x; t < ntiles; t += gridDim.x) {
        f32x4 acc = {0.f, 0.f, 0.f, 0.f};
        size_t rowoff = (size_t)(t * 16 + lm) * K + lk * 8;
#pragma unroll
        for (int ks = 0; ks < K / 32; ++ks) {
            bf16x8 afrag;
            if (A_F32) {
                float4 v0 = *(const float4*)(Xf + rowoff + ks * 32);
                float4 v1 = *(const float4*)(Xf + rowoff + ks * 32 + 4);
                afrag[0] = (bf16_t)v0.x; afrag[1] = (bf16_t)v0.y;
                afrag[2] = (bf16_t)v0.z; afrag[3] = (bf16_t)v0.w;
                afrag[4] = (bf16_t)v1.x; afrag[5] = (bf16_t)v1.y;
                afrag[6] = (bf16_t)v1.z; afrag[7] = (bf16_t)v1.w;
            } else {
                afrag = *(const bf16x8*)(Xb + rowoff + ks * 32);
            }
            acc = __builtin_amdgcn_mfma_f32_16x16x32_bf16(afrag, bfrag[ks], acc, 0, 0, 0);
        }
#pragma unroll
        for (int r = 0; r < 4; ++r) {
            int row = t * 16 + lk * 4 + r;
            outb[(size_t)row * 64 + colbase + lm] = (bf16_t)(acc[r] * dinv[row]);
        }
    }
}

// ---------------- fused gather-conv: out = dinv[dst]*(hp[dst]+Σ ew*hp[src]) + b; l2norm; relu

template <typename OT>
__global__ void k_conv(const bf16_t* __restrict__ P, const int* __restrict__ row_ptr,
                       const int2* __restrict__ meta, const float* __restrict__ dinv,
                       const float* __restrict__ b, OT* __restrict__ Q, int n_nodes) {
    int lane = threadIdx.x & 63;
    int w = blockIdx.x * (blockDim.x >> 6) + (threadIdx.x >> 6);
    int nw = gridDim.x * (blockDim.x >> 6);
    for (int nd = w; nd < n_nodes; nd += nw) {
        float acc = (float)P[(size_t)nd * 64 + lane];
        int e = row_ptr[nd], end = row_ptr[nd + 1];
        for (; e + 3 < end; e += 4) {
            int2 m0 = meta[e], m1 = meta[e + 1], m2 = meta[e + 2], m3 = meta[e + 3];
            float p0 = (float)P[(size_t)m0.x * 64 + lane];
            float p1 = (float)P[(size_t)m1.x * 64 + lane];
            float p2 = (float)P[(size_t)m2.x * 64 + lane];
            float p3 = (float)P[(size_t)m3.x * 64 + lane];
            acc = fmaf(__int_as_float(m0.y), p0, acc);
            acc = fmaf(__int_as_float(m1.y), p1, acc);
            acc = fmaf(__int_as_float(m2.y), p2, acc);
            acc = fmaf(__int_as_float(m3.y), p3, acc);
        }
        for (; e < end; ++e) {
            int2 m = meta[e];
            acc = fmaf(__int_as_float(m.y), (float)P[(size_t)m.x * 64 + lane], acc);
        }
        acc = dinv[nd] * acc + b[lane];
        float ss = acc * acc;
#pragma unroll
        for (int off = 32; off; off >>= 1) ss += __shfl_xor(ss, off, 64);
        float o = fmaxf(acc / fmaxf(sqrtf(ss), 1e-12f), 0.f);
        Q[(size_t)nd * 64 + lane] = (OT)o;
    }
}

// ---------------- segmented pool (batch sorted) ----------------

__global__ void k_starts(const int* __restrict__ batch, int* __restrict__ starts,
                         int N, int G) {
    int g = blockIdx.x * blockDim.x + threadIdx.x;
    if (g > G) return;
    int lo = 0, hi = N;
    while (lo < hi) {
        int mid = (lo + hi) >> 1;
        if (batch[mid] < g) lo = mid + 1; else hi = mid;
    }
    starts[g] = lo;
}

__global__ void k_pool(const float* __restrict__ Q, const int* __restrict__ starts,
                       float* __restrict__ pooled, int G) {
    int lane = threadIdx.x & 63;
    int w = blockIdx.x * (blockDim.x >> 6) + (threadIdx.x >> 6);
    if (w >= G) return;
    float acc = 0.f;
    int end = starts[w + 1];
    for (int i = starts[w]; i < end; ++i) acc += Q[(size_t)i * 64 + lane];
    pooled[(size_t)w * 64 + lane] = acc;
}

// ---------------- per-graph MLP + log_softmax ----------------

__global__ void k_mlp(const float* __restrict__ pooled,
                      const float* __restrict__ fc1w, const float* __restrict__ fc1b,
                      const float* __restrict__ fc2w, const float* __restrict__ fc2b,
                      float* __restrict__ out, int G) {
    __shared__ float sp[64];
    __shared__ float sz[64];
    __shared__ float sl[10];
    __shared__ float slse;
    int g = blockIdx.x;
    int t = threadIdx.x;
    if (g >= G) return;
    sp[t] = pooled[(size_t)g * 64 + t];
    __syncthreads();
    float acc = fc1b[t];
#pragma unroll
    for (int k = 0; k < 64; ++k) acc += sp[k] * fc1w[k * 64 + t];
    sz[t] = fmaxf(acc, 0.f);
    __syncthreads();
    if (t < 10) {
        float a = fc2b[t];
#pragma unroll
        for (int j = 0; j < 64; ++j) a += sz[j] * fc2w[j * 10 + t];
        sl[t] = a;
    }
    __syncthreads();
    if (t == 0) {
        float m = sl[0];
        for (int c = 1; c < 10; ++c) m = fmaxf(m, sl[c]);
        float s = 0.f;
        for (int c = 0; c < 10; ++c) s += expf(sl[c] - m);
        slse = m + logf(s);
    }
    __syncthreads();
    if (t < 10) out[(size_t)g * 10 + t] = sl[t] - slse;
}

// ---------------- launch ----------------

extern "C" void kernel_launch(void* const* d_in, const int* in_sizes, int n_in,
                              void* d_out, int out_size, void* d_ws, size_t ws_size,
                              hipStream_t stream) {
    const float* x     = (const float*)d_in[0];
    const int*   ei    = (const int*)d_in[1];
    const int*   batch = (const int*)d_in[2];
    const float* ew    = (const float*)d_in[3];
    const float* W1 = (const float*)d_in[4];
    const float* b1 = (const float*)d_in[5];
    const float* W2 = (const float*)d_in[6];
    const float* b2 = (const float*)d_in[7];
    const float* W3 = (const float*)d_in[8];
    const float* b3 = (const float*)d_in[9];
    const float* fc1w = (const float*)d_in[10];
    const float* fc1b = (const float*)d_in[11];
    const float* fc2w = (const float*)d_in[12];
    const float* fc2b = (const float*)d_in[13];
    float* out = (float*)d_out;

    const int N = in_sizes[0] / 128;   // 100000 (multiple of 16)
    const int E = in_sizes[1] / 2;     // 3200000
    const int G = out_size / 10;       // 512
    const int NB = (N + 127) / 128;    // 782 buckets (<=1024)

    // workspace (256B-aligned chunks)
    char* wp = (char*)d_ws;
    auto alloc = [&](size_t bytes) {
        char* p = wp;
        wp += (bytes + 255) & ~(size_t)255;
        return p;
    };
    size_t qbytes = (size_t)N * 64 * 4;
    size_t rbytes = (size_t)E * 8;
    // Q region double-duty: Pass B/C records first, then conv outputs (records dead by then)
    char*   Qreg    = alloc(qbytes > rbytes ? qbytes : rbytes);
    float*  Qf      = (float*)Qreg;
    bf16_t* Qb      = (bf16_t*)Qreg;
    int2*   rec     = (int2*)Qreg;
    bf16_t* P       = (bf16_t*)alloc((size_t)N * 64 * 2);
    int2*   meta    = (int2*) alloc((size_t)E * 8);
    int*    row_ptr = (int*)  alloc((size_t)(N + 1) * 4);
    float*  dinv    = (float*)alloc((size_t)N * 4);
    float*  pooled  = (float*)alloc((size_t)G * 64 * 4);
    int*    starts  = (int*)  alloc((size_t)(G + 1) * 4);
    int*    btot    = (int*)  alloc((size_t)NB * 4);
    int*    bstart  = (int*)  alloc((size_t)(NB + 1) * 4);
    int*    bcur    = (int*)  alloc((size_t)NB * 4);

    dim3 blk(256);
    dim3 g2048(2048);
    dim3 g1024(1024);
    const int ntiles = N / 16;                         // 6250
    const int nblkB  = (E + BTILE - 1) / BTILE;        // 196

    // CSR build: bucket histogram -> scan -> bin -> per-bucket sort (+dinv, row_ptr)
    k_fill_i<<<dim3(64), blk, 0, stream>>>(btot, 0, NB);
    k_bucket_hist<<<dim3(256), blk, 0, stream>>>(ei + E, E, NB, btot);
    k_bucket_scan<<<dim3(1), dim3(1024), 0, stream>>>(btot, bstart, bcur, NB);
    k_passB<<<dim3(nblkB), blk, 0, stream>>>(ei, ew, bstart, bcur, rec, E, NB);
    k_passC<<<dim3(NB), blk, 0, stream>>>(rec, bstart, row_ptr, dinv, meta, N, E);
    k_starts<<<dim3(4), blk, 0, stream>>>(batch, starts, N, G);

    // conv1 (K=128, f32 A)   [rec region is dead from here on; Q reuses it]
    k_gemm_mfma<128, true><<<g1024, blk, 0, stream>>>(x, W1, dinv, P, ntiles);
    k_conv<bf16_t><<<g2048, blk, 0, stream>>>(P, row_ptr, meta, dinv, b1, Qb, N);
    // conv2 (K=64, bf16 A)
    k_gemm_mfma<64, false><<<g1024, blk, 0, stream>>>(Qb, W2, dinv, P, ntiles);
    k_conv<bf16_t><<<g2048, blk, 0, stream>>>(P, row_ptr, meta, dinv, b2, Qb, N);
    // conv3 (K=64, bf16 A, f32 node output for pooling)
    k_gemm_mfma<64, false><<<g1024, blk, 0, stream>>>(Qb, W3, dinv, P, ntiles);
    k_conv<float><<<g2048, blk, 0, stream>>>(P, row_ptr, meta, dinv, b3, Qf, N);

    // pool + MLP
    k_pool<<<dim3((G * 64 + 255) / 256), blk, 0, stream>>>(Qf, starts, pooled, G);
    k_mlp<<<dim3(G), dim3(64), 0, stream>>>(pooled, fc1w, fc1b, fc2w, fc2b, out, G);
}

// Round 6
// 493.077 us; speedup vs baseline: 5.0594x; 1.2560x over previous
//
#include <hip/hip_runtime.h>
#include <math.h>

typedef __bf16 bf16_t;
typedef __attribute__((ext_vector_type(4))) __bf16 bf16x4;
typedef __attribute__((ext_vector_type(8))) __bf16 bf16x8;
typedef __attribute__((ext_vector_type(4))) float f32x4;

#define BTILE 16384

// ---------------- fills ----------------

__global__ void k_fill_i(int* __restrict__ p, int v, int n) {
    int i = blockIdx.x * blockDim.x + threadIdx.x;
    int s = gridDim.x * blockDim.x;
    for (; i < n; i += s) p[i] = v;
}

// ---------------- Pass A: bucket histogram (bucket = dst>>7) ----------------

__global__ void k_bucket_hist(const int* __restrict__ dstp, int E, int NB,
                              int* __restrict__ btot) {
    __shared__ int lh[1024];
    for (int i = threadIdx.x; i < 1024; i += blockDim.x) lh[i] = 0;
    __syncthreads();
    int i = blockIdx.x * blockDim.x + threadIdx.x;
    int s = gridDim.x * blockDim.x;
    for (; i < E; i += s) atomicAdd(&lh[dstp[i] >> 7], 1);
    __syncthreads();
    for (int b = threadIdx.x; b < NB; b += blockDim.x) {
        int c = lh[b];
        if (c) atomicAdd(&btot[b], c);
    }
}

// ---------------- bucket scan: btot -> bstart[NB+1], zero bcur ----------------

__global__ void k_bucket_scan(const int* __restrict__ btot, int* __restrict__ bstart,
                              int* __restrict__ bcur, int NB) {
    __shared__ int v[1024];
    int t = threadIdx.x;
    int orig = (t < NB) ? btot[t] : 0;
    v[t] = orig;
    __syncthreads();
    for (int off = 1; off < 1024; off <<= 1) {
        int add = (t >= off) ? v[t - off] : 0;
        __syncthreads();
        v[t] += add;
        __syncthreads();
    }
    if (t < NB) { bstart[t] = v[t] - orig; bcur[t] = 0; }
    if (t == NB - 1) bstart[NB] = v[t];
}

// ---------------- Pass B: bin records into bucket regions ----------------
// record.x = (dst&127)<<17 | src  (src < 131072), record.y = ew bits

__global__ __launch_bounds__(256) void k_passB(const int* __restrict__ ei,
        const float* __restrict__ ew, const int* __restrict__ bstart,
        int* __restrict__ bcur, int2* __restrict__ rec_out, int E, int NB) {
    __shared__ int lhist[1024];
    __shared__ int base[1024];
    __shared__ unsigned short lrank[BTILE];
    const int* dstp = ei + E;
    int tile0 = blockIdx.x * BTILE;
    for (int i = threadIdx.x; i < 1024; i += 256) lhist[i] = 0;
    __syncthreads();
#pragma unroll 4
    for (int j = 0; j < BTILE / 256; ++j) {
        int idx = j * 256 + threadIdx.x;
        int e = tile0 + idx;
        if (e < E) {
            int b = dstp[e] >> 7;
            lrank[idx] = (unsigned short)atomicAdd(&lhist[b], 1);
        }
    }
    __syncthreads();
    for (int b = threadIdx.x; b < NB; b += 256) {
        int c = lhist[b];
        if (c) base[b] = bstart[b] + atomicAdd(&bcur[b], c);
    }
    __syncthreads();
#pragma unroll 4
    for (int j = 0; j < BTILE / 256; ++j) {
        int idx = j * 256 + threadIdx.x;
        int e = tile0 + idx;
        if (e < E) {
            int d = dstp[e];
            int b = d >> 7;
            rec_out[base[b] + lrank[idx]] =
                make_int2(((d & 127) << 17) | ei[e], __float_as_int(ew[e]));
        }
    }
}

// ---------------- Pass C: per-bucket counting sort -> meta, row_ptr, dinv ----------------

__global__ __launch_bounds__(256) void k_passC(const int2* __restrict__ rec_in,
        const int* __restrict__ bstart, int* __restrict__ row_ptr,
        float* __restrict__ dinv, int2* __restrict__ meta, int N, int E) {
    __shared__ int nh[128];
    __shared__ float sw[128];
    __shared__ int offs[128];
    __shared__ int cur[128];
    int b = blockIdx.x, t = threadIdx.x;
    int rs = bstart[b], re = bstart[b + 1];
    if (t < 128) { nh[t] = 0; sw[t] = 0.f; cur[t] = 0; }
    __syncthreads();
    for (int i = rs + t; i < re; i += 256) {
        int2 r = rec_in[i];
        int dl = r.x >> 17;
        atomicAdd(&nh[dl], 1);
        atomicAdd(&sw[dl], __int_as_float(r.y));
    }
    __syncthreads();
    if (t == 0) {
        int s = 0;
        for (int k = 0; k < 128; ++k) { offs[k] = s; s += nh[k]; }
    }
    __syncthreads();
    if (t < 128) {
        int node = b * 128 + t;
        if (node < N) {
            row_ptr[node] = rs + offs[t];
            dinv[node] = rsqrtf(1.f + sw[t]);
        }
    }
    if (b == 0 && t == 0) row_ptr[N] = E;
    __syncthreads();
    for (int i = rs + t; i < re; i += 256) {
        int2 r = rec_in[i];
        int dl = r.x >> 17;
        int pos = rs + offs[dl] + atomicAdd(&cur[dl], 1);
        meta[pos] = make_int2(r.x & 0x1FFFF, r.y);
    }
}

// ---------------- MFMA GEMM: out[n][f] = dinv[n] * (X[n][:] @ W[:][f]) ----------------

template <int K, bool A_F32>
__global__ __launch_bounds__(256) void k_gemm_mfma(
        const void* __restrict__ Xv, const float* __restrict__ W,
        const float* __restrict__ dinv, bf16_t* __restrict__ outb, int ntiles) {
    __shared__ bf16_t sWt[64 * K];              // transposed W: sWt[c*K + k]
    for (int idx = threadIdx.x; idx < K * 64; idx += blockDim.x) {
        int k = idx >> 6, c = idx & 63;
        sWt[c * K + k] = (bf16_t)W[idx];
    }
    __syncthreads();

    int lane = threadIdx.x & 63;
    int wid  = threadIdx.x >> 6;
    int colbase = wid * 16;
    int lm = lane & 15;
    int lk = lane >> 4;

    bf16x8 bfrag[K / 32];
#pragma unroll
    for (int ks = 0; ks < K / 32; ++ks)
        bfrag[ks] = *(const bf16x8*)&sWt[(colbase + lm) * K + ks * 32 + lk * 8];

    const float*  Xf = (const float*)Xv;
    const bf16_t* Xb = (const bf16_t*)Xv;

    for (int t = blockIdx.x; t < ntiles; t += gridDim.x) {
        f32x4 acc = {0.f, 0.f, 0.f, 0.f};
        size_t rowoff = (size_t)(t * 16 + lm) * K + lk * 8;
#pragma unroll
        for (int ks = 0; ks < K / 32; ++ks) {
            bf16x8 afrag;
            if (A_F32) {
                float4 v0 = *(const float4*)(Xf + rowoff + ks * 32);
                float4 v1 = *(const float4*)(Xf + rowoff + ks * 32 + 4);
                afrag[0] = (bf16_t)v0.x; afrag[1] = (bf16_t)v0.y;
                afrag[2] = (bf16_t)v0.z; afrag[3] = (bf16_t)v0.w;
                afrag[4] = (bf16_t)v1.x; afrag[5] = (bf16_t)v1.y;
                afrag[6] = (bf16_t)v1.z; afrag[7] = (bf16_t)v1.w;
            } else {
                afrag = *(const bf16x8*)(Xb + rowoff + ks * 32);
            }
            acc = __builtin_amdgcn_mfma_f32_16x16x32_bf16(afrag, bfrag[ks], acc, 0, 0, 0);
        }
#pragma unroll
        for (int r = 0; r < 4; ++r) {
            int row = t * 16 + lk * 4 + r;
            outb[(size_t)row * 64 + colbase + lm] = (bf16_t)(acc[r] * dinv[row]);
        }
    }
}

// ---------------- fused gather-conv, 4 nodes per wave ----------------
// group g = lane>>4 owns node q*4+g; lane fl = lane&15 owns feats 4fl..4fl+3.
// out = dinv[dst]*(P[dst] + Σ ew*P[src]) + b ; row l2norm ; relu

template <bool F32OUT>
__global__ __launch_bounds__(256) void k_conv4(
        const bf16_t* __restrict__ P, const int* __restrict__ row_ptr,
        const int2* __restrict__ meta, const float* __restrict__ dinv,
        const float* __restrict__ b, bf16_t* __restrict__ Qb,
        float* __restrict__ Qf, int n_nodes) {
    int lane = threadIdx.x & 63;
    int g  = lane >> 4;
    int fl = lane & 15;
    int wave  = blockIdx.x * (blockDim.x >> 6) + (threadIdx.x >> 6);
    int nwave = gridDim.x * (blockDim.x >> 6);
    int nquads = (n_nodes + 3) >> 2;

    float4 bv = *(const float4*)(b + fl * 4);

    for (int q = wave; q < nquads; q += nwave) {
        int nd = q * 4 + g;
        bool act = nd < n_nodes;
        int ndc = act ? nd : 0;

        int beg = row_ptr[ndc];
        int end = row_ptr[ndc + 1];

        bf16x4 sv = *(const bf16x4*)(P + (size_t)ndc * 64 + fl * 4);
        float a0 = (float)sv[0], a1 = (float)sv[1], a2 = (float)sv[2], a3 = (float)sv[3];
        float c0 = 0.f, c1 = 0.f, c2 = 0.f, c3 = 0.f;

        int e = beg;
        for (; e + 1 < end; e += 2) {
            int2 m0 = meta[e];
            int2 m1 = meta[e + 1];
            bf16x4 p0 = *(const bf16x4*)(P + (size_t)m0.x * 64 + fl * 4);
            bf16x4 p1 = *(const bf16x4*)(P + (size_t)m1.x * 64 + fl * 4);
            float w0 = __int_as_float(m0.y);
            float w1 = __int_as_float(m1.y);
            a0 = fmaf(w0, (float)p0[0], a0);
            a1 = fmaf(w0, (float)p0[1], a1);
            a2 = fmaf(w0, (float)p0[2], a2);
            a3 = fmaf(w0, (float)p0[3], a3);
            c0 = fmaf(w1, (float)p1[0], c0);
            c1 = fmaf(w1, (float)p1[1], c1);
            c2 = fmaf(w1, (float)p1[2], c2);
            c3 = fmaf(w1, (float)p1[3], c3);
        }
        if (e < end) {
            int2 m = meta[e];
            bf16x4 p = *(const bf16x4*)(P + (size_t)m.x * 64 + fl * 4);
            float w = __int_as_float(m.y);
            a0 = fmaf(w, (float)p[0], a0);
            a1 = fmaf(w, (float)p[1], a1);
            a2 = fmaf(w, (float)p[2], a2);
            a3 = fmaf(w, (float)p[3], a3);
        }
        a0 += c0; a1 += c1; a2 += c2; a3 += c3;

        float dn = dinv[ndc];
        a0 = fmaf(dn, a0, bv.x);
        a1 = fmaf(dn, a1, bv.y);
        a2 = fmaf(dn, a2, bv.z);
        a3 = fmaf(dn, a3, bv.w);

        float ss = a0 * a0 + a1 * a1 + a2 * a2 + a3 * a3;
        ss += __shfl_xor(ss, 1, 64);
        ss += __shfl_xor(ss, 2, 64);
        ss += __shfl_xor(ss, 4, 64);
        ss += __shfl_xor(ss, 8, 64);
        float inv = 1.0f / fmaxf(sqrtf(ss), 1e-12f);
        a0 = fmaxf(a0 * inv, 0.f);
        a1 = fmaxf(a1 * inv, 0.f);
        a2 = fmaxf(a2 * inv, 0.f);
        a3 = fmaxf(a3 * inv, 0.f);

        if (act) {
            if (F32OUT) {
                float4 o = {a0, a1, a2, a3};
                *(float4*)(Qf + (size_t)nd * 64 + fl * 4) = o;
            } else {
                bf16x4 o;
                o[0] = (bf16_t)a0; o[1] = (bf16_t)a1;
                o[2] = (bf16_t)a2; o[3] = (bf16_t)a3;
                *(bf16x4*)(Qb + (size_t)nd * 64 + fl * 4) = o;
            }
        }
    }
}

// ---------------- segmented pool (batch sorted) ----------------

__global__ void k_starts(const int* __restrict__ batch, int* __restrict__ starts,
                         int N, int G) {
    int g = blockIdx.x * blockDim.x + threadIdx.x;
    if (g > G) return;
    int lo = 0, hi = N;
    while (lo < hi) {
        int mid = (lo + hi) >> 1;
        if (batch[mid] < g) lo = mid + 1; else hi = mid;
    }
    starts[g] = lo;
}

__global__ void k_pool(const float* __restrict__ Q, const int* __restrict__ starts,
                       float* __restrict__ pooled, int G) {
    int lane = threadIdx.x & 63;
    int w = blockIdx.x * (blockDim.x >> 6) + (threadIdx.x >> 6);
    if (w >= G) return;
    float acc = 0.f;
    int end = starts[w + 1];
    for (int i = starts[w]; i < end; ++i) acc += Q[(size_t)i * 64 + lane];
    pooled[(size_t)w * 64 + lane] = acc;
}

// ---------------- per-graph MLP + log_softmax ----------------

__global__ void k_mlp(const float* __restrict__ pooled,
                      const float* __restrict__ fc1w, const float* __restrict__ fc1b,
                      const float* __restrict__ fc2w, const float* __restrict__ fc2b,
                      float* __restrict__ out, int G) {
    __shared__ float sp[64];
    __shared__ float sz[64];
    __shared__ float sl[10];
    __shared__ float slse;
    int g = blockIdx.x;
    int t = threadIdx.x;
    if (g >= G) return;
    sp[t] = pooled[(size_t)g * 64 + t];
    __syncthreads();
    float acc = fc1b[t];
#pragma unroll
    for (int k = 0; k < 64; ++k) acc += sp[k] * fc1w[k * 64 + t];
    sz[t] = fmaxf(acc, 0.f);
    __syncthreads();
    if (t < 10) {
        float a = fc2b[t];
#pragma unroll
        for (int j = 0; j < 64; ++j) a += sz[j] * fc2w[j * 10 + t];
        sl[t] = a;
    }
    __syncthreads();
    if (t == 0) {
        float m = sl[0];
        for (int c = 1; c < 10; ++c) m = fmaxf(m, sl[c]);
        float s = 0.f;
        for (int c = 0; c < 10; ++c) s += expf(sl[c] - m);
        slse = m + logf(s);
    }
    __syncthreads();
    if (t < 10) out[(size_t)g * 10 + t] = sl[t] - slse;
}

// ---------------- launch ----------------

extern "C" void kernel_launch(void* const* d_in, const int* in_sizes, int n_in,
                              void* d_out, int out_size, void* d_ws, size_t ws_size,
                              hipStream_t stream) {
    const float* x     = (const float*)d_in[0];
    const int*   ei    = (const int*)d_in[1];
    const int*   batch = (const int*)d_in[2];
    const float* ew    = (const float*)d_in[3];
    const float* W1 = (const float*)d_in[4];
    const float* b1 = (const float*)d_in[5];
    const float* W2 = (const float*)d_in[6];
    const float* b2 = (const float*)d_in[7];
    const float* W3 = (const float*)d_in[8];
    const float* b3 = (const float*)d_in[9];
    const float* fc1w = (const float*)d_in[10];
    const float* fc1b = (const float*)d_in[11];
    const float* fc2w = (const float*)d_in[12];
    const float* fc2b = (const float*)d_in[13];
    float* out = (float*)d_out;

    const int N = in_sizes[0] / 128;   // 100000 (multiple of 16)
    const int E = in_sizes[1] / 2;     // 3200000
    const int G = out_size / 10;       // 512
    const int NB = (N + 127) / 128;    // 782 buckets (<=1024)

    // workspace (256B-aligned chunks)
    char* wp = (char*)d_ws;
    auto alloc = [&](size_t bytes) {
        char* p = wp;
        wp += (bytes + 255) & ~(size_t)255;
        return p;
    };
    size_t qbytes = (size_t)N * 64 * 4;
    size_t rbytes = (size_t)E * 8;
    // Q region double-duty: Pass B/C records first, then conv outputs (records dead by then)
    char*   Qreg    = alloc(qbytes > rbytes ? qbytes : rbytes);
    float*  Qf      = (float*)Qreg;
    bf16_t* Qb      = (bf16_t*)Qreg;
    int2*   rec     = (int2*)Qreg;
    bf16_t* P       = (bf16_t*)alloc((size_t)N * 64 * 2);
    int2*   meta    = (int2*) alloc((size_t)E * 8);
    int*    row_ptr = (int*)  alloc((size_t)(N + 1) * 4);
    float*  dinv    = (float*)alloc((size_t)N * 4);
    float*  pooled  = (float*)alloc((size_t)G * 64 * 4);
    int*    starts  = (int*)  alloc((size_t)(G + 1) * 4);
    int*    btot    = (int*)  alloc((size_t)NB * 4);
    int*    bstart  = (int*)  alloc((size_t)(NB + 1) * 4);
    int*    bcur    = (int*)  alloc((size_t)NB * 4);

    dim3 blk(256);
    dim3 g1024(1024);
    const int ntiles = N / 16;                         // 6250
    const int nblkB  = (E + BTILE - 1) / BTILE;        // 196
    const int nquads = (N + 3) / 4;                    // 25000
    dim3 gconv((nquads + 3) / 4);                      // 6250 blocks, 1 quad/wave

    // CSR build: bucket histogram -> scan -> bin -> per-bucket sort (+dinv, row_ptr)
    k_fill_i<<<dim3(64), blk, 0, stream>>>(btot, 0, NB);
    k_bucket_hist<<<dim3(256), blk, 0, stream>>>(ei + E, E, NB, btot);
    k_bucket_scan<<<dim3(1), dim3(1024), 0, stream>>>(btot, bstart, bcur, NB);
    k_passB<<<dim3(nblkB), blk, 0, stream>>>(ei, ew, bstart, bcur, rec, E, NB);
    k_passC<<<dim3(NB), blk, 0, stream>>>(rec, bstart, row_ptr, dinv, meta, N, E);
    k_starts<<<dim3(4), blk, 0, stream>>>(batch, starts, N, G);

    // conv1 (K=128, f32 A)   [rec region is dead from here on; Q reuses it]
    k_gemm_mfma<128, true><<<g1024, blk, 0, stream>>>(x, W1, dinv, P, ntiles);
    k_conv4<false><<<gconv, blk, 0, stream>>>(P, row_ptr, meta, dinv, b1, Qb, nullptr, N);
    // conv2 (K=64, bf16 A)
    k_gemm_mfma<64, false><<<g1024, blk, 0, stream>>>(Qb, W2, dinv, P, ntiles);
    k_conv4<false><<<gconv, blk, 0, stream>>>(P, row_ptr, meta, dinv, b2, Qb, nullptr, N);
    // conv3 (K=64, bf16 A, f32 node output for pooling)
    k_gemm_mfma<64, false><<<g1024, blk, 0, stream>>>(Qb, W3, dinv, P, ntiles);
    k_conv4<true><<<gconv, blk, 0, stream>>>(P, row_ptr, meta, dinv, b3, nullptr, Qf, N);

    // pool + MLP
    k_pool<<<dim3((G * 64 + 255) / 256), blk, 0, stream>>>(Qf, starts, pooled, G);
    k_mlp<<<dim3(G), dim3(64), 0, stream>>>(pooled, fc1w, fc1b, fc2w, fc2b, out, G);
}

// Round 7
// 458.707 us; speedup vs baseline: 5.4385x; 1.0749x over previous
//
#include <hip/hip_runtime.h>
#include <math.h>

typedef __bf16 bf16_t;
typedef __attribute__((ext_vector_type(4))) __bf16 bf16x4;
typedef __attribute__((ext_vector_type(8))) __bf16 bf16x8;
typedef __attribute__((ext_vector_type(4))) float f32x4;

#define BTILE 4096

// ---------------- fills ----------------

__global__ void k_fill_i(int* __restrict__ p, int v, int n) {
    int i = blockIdx.x * blockDim.x + threadIdx.x;
    int s = gridDim.x * blockDim.x;
    for (; i < n; i += s) p[i] = v;
}

// ---------------- Pass A: bucket histogram (bucket = dst>>7) ----------------

__global__ void k_bucket_hist(const int* __restrict__ dstp, int E, int NB,
                              int* __restrict__ btot) {
    __shared__ int lh[1024];
    for (int i = threadIdx.x; i < 1024; i += blockDim.x) lh[i] = 0;
    __syncthreads();
    int i = blockIdx.x * blockDim.x + threadIdx.x;
    int s = gridDim.x * blockDim.x;
    for (; i < E; i += s) atomicAdd(&lh[dstp[i] >> 7], 1);
    __syncthreads();
    for (int b = threadIdx.x; b < NB; b += blockDim.x) {
        int c = lh[b];
        if (c) atomicAdd(&btot[b], c);
    }
}

// ---------------- bucket scan: btot -> bstart[NB+1], zero bcur ----------------

__global__ void k_bucket_scan(const int* __restrict__ btot, int* __restrict__ bstart,
                              int* __restrict__ bcur, int NB) {
    __shared__ int v[1024];
    int t = threadIdx.x;
    int orig = (t < NB) ? btot[t] : 0;
    v[t] = orig;
    __syncthreads();
    for (int off = 1; off < 1024; off <<= 1) {
        int add = (t >= off) ? v[t - off] : 0;
        __syncthreads();
        v[t] += add;
        __syncthreads();
    }
    if (t < NB) { bstart[t] = v[t] - orig; bcur[t] = 0; }
    if (t == NB - 1) bstart[NB] = v[t];
}

// ---------------- Pass B: bin records into bucket regions ----------------
// record.x = (dst&127)<<17 | src  (src < 131072), record.y = ew bits
// rank kept in REGISTERS (each thread re-visits the same 8 edges in phase 2).

__global__ __launch_bounds__(512) void k_passB(const int* __restrict__ ei,
        const float* __restrict__ ew, const int* __restrict__ bstart,
        int* __restrict__ bcur, int2* __restrict__ rec_out, int E, int NB) {
    __shared__ int lhist[1024];
    __shared__ int base[1024];
    const int* dstp = ei + E;
    int tile0 = blockIdx.x * BTILE;
    int t = threadIdx.x;
    for (int i = t; i < 1024; i += 512) lhist[i] = 0;
    __syncthreads();
    int rank[BTILE / 512];
#pragma unroll
    for (int j = 0; j < BTILE / 512; ++j) {
        int e = tile0 + j * 512 + t;
        if (e < E) rank[j] = atomicAdd(&lhist[dstp[e] >> 7], 1);
    }
    __syncthreads();
    for (int b = t; b < NB; b += 512) {
        int c = lhist[b];
        if (c) base[b] = bstart[b] + atomicAdd(&bcur[b], c);
    }
    __syncthreads();
#pragma unroll
    for (int j = 0; j < BTILE / 512; ++j) {
        int e = tile0 + j * 512 + t;
        if (e < E) {
            int d = dstp[e];
            int b = d >> 7;
            rec_out[base[b] + rank[j]] =
                make_int2(((d & 127) << 17) | ei[e], __float_as_int(ew[e]));
        }
    }
}

// ---------------- Pass C: per-bucket counting sort -> meta, row_ptr, dinv ----------------

__global__ __launch_bounds__(256) void k_passC(const int2* __restrict__ rec_in,
        const int* __restrict__ bstart, int* __restrict__ row_ptr,
        float* __restrict__ dinv, int2* __restrict__ meta, int N, int E) {
    __shared__ int nh[128];
    __shared__ float sw[128];
    __shared__ int offs[128];
    __shared__ int cur[128];
    int b = blockIdx.x, t = threadIdx.x;
    int rs = bstart[b], re = bstart[b + 1];
    if (t < 128) { nh[t] = 0; sw[t] = 0.f; cur[t] = 0; }
    __syncthreads();
    for (int i = rs + t; i < re; i += 256) {
        int2 r = rec_in[i];
        int dl = r.x >> 17;
        atomicAdd(&nh[dl], 1);
        atomicAdd(&sw[dl], __int_as_float(r.y));
    }
    __syncthreads();
    if (t == 0) {
        int s = 0;
        for (int k = 0; k < 128; ++k) { offs[k] = s; s += nh[k]; }
    }
    __syncthreads();
    if (t < 128) {
        int node = b * 128 + t;
        if (node < N) {
            row_ptr[node] = rs + offs[t];
            dinv[node] = rsqrtf(1.f + sw[t]);
        }
    }
    if (b == 0 && t == 0) row_ptr[N] = E;
    __syncthreads();
    for (int i = rs + t; i < re; i += 256) {
        int2 r = rec_in[i];
        int dl = r.x >> 17;
        int pos = rs + offs[dl] + atomicAdd(&cur[dl], 1);
        meta[pos] = make_int2(r.x & 0x1FFFF, r.y);
    }
}

// ---------------- MFMA GEMM: out[n][f] = dinv[n] * (X[n][:] @ W[:][f]) ----------------

template <int K, bool A_F32>
__global__ __launch_bounds__(256) void k_gemm_mfma(
        const void* __restrict__ Xv, const float* __restrict__ W,
        const float* __restrict__ dinv, bf16_t* __restrict__ outb, int ntiles) {
    __shared__ bf16_t sWt[64 * K];              // transposed W: sWt[c*K + k]
    for (int idx = threadIdx.x; idx < K * 64; idx += blockDim.x) {
        int k = idx >> 6, c = idx & 63;
        sWt[c * K + k] = (bf16_t)W[idx];
    }
    __syncthreads();

    int lane = threadIdx.x & 63;
    int wid  = threadIdx.x >> 6;
    int colbase = wid * 16;
    int lm = lane & 15;
    int lk = lane >> 4;

    bf16x8 bfrag[K / 32];
#pragma unroll
    for (int ks = 0; ks < K / 32; ++ks)
        bfrag[ks] = *(const bf16x8*)&sWt[(colbase + lm) * K + ks * 32 + lk * 8];

    const float*  Xf = (const float*)Xv;
    const bf16_t* Xb = (const bf16_t*)Xv;

    for (int t = blockIdx.x; t < ntiles; t += gridDim.x) {
        f32x4 acc = {0.f, 0.f, 0.f, 0.f};
        size_t rowoff = (size_t)(t * 16 + lm) * K + lk * 8;
#pragma unroll
        for (int ks = 0; ks < K / 32; ++ks) {
            bf16x8 afrag;
            if (A_F32) {
                float4 v0 = *(const float4*)(Xf + rowoff + ks * 32);
                float4 v1 = *(const float4*)(Xf + rowoff + ks * 32 + 4);
                afrag[0] = (bf16_t)v0.x; afrag[1] = (bf16_t)v0.y;
                afrag[2] = (bf16_t)v0.z; afrag[3] = (bf16_t)v0.w;
                afrag[4] = (bf16_t)v1.x; afrag[5] = (bf16_t)v1.y;
                afrag[6] = (bf16_t)v1.z; afrag[7] = (bf16_t)v1.w;
            } else {
                afrag = *(const bf16x8*)(Xb + rowoff + ks * 32);
            }
            acc = __builtin_amdgcn_mfma_f32_16x16x32_bf16(afrag, bfrag[ks], acc, 0, 0, 0);
        }
#pragma unroll
        for (int r = 0; r < 4; ++r) {
            int row = t * 16 + lk * 4 + r;
            outb[(size_t)row * 64 + colbase + lm] = (bf16_t)(acc[r] * dinv[row]);
        }
    }
}

// ---------------- fused gather-conv, 4 nodes per wave, 4 edges/iter ----------------
// group g = lane>>4 owns node q*4+g; lane fl = lane&15 owns feats 4fl..4fl+3.
// out = dinv[dst]*(P[dst] + Σ ew*P[src]) + b ; row l2norm ; relu

template <bool F32OUT>
__global__ __launch_bounds__(256) void k_conv4(
        const bf16_t* __restrict__ P, const int* __restrict__ row_ptr,
        const int2* __restrict__ meta, const float* __restrict__ dinv,
        const float* __restrict__ b, bf16_t* __restrict__ Qb,
        float* __restrict__ Qf, int n_nodes) {
    int lane = threadIdx.x & 63;
    int g  = lane >> 4;
    int fl = lane & 15;
    int wave  = blockIdx.x * (blockDim.x >> 6) + (threadIdx.x >> 6);
    int nwave = gridDim.x * (blockDim.x >> 6);
    int nquads = (n_nodes + 3) >> 2;

    float4 bv = *(const float4*)(b + fl * 4);

    for (int q = wave; q < nquads; q += nwave) {
        int nd = q * 4 + g;
        bool act = nd < n_nodes;
        int ndc = act ? nd : 0;

        int beg = row_ptr[ndc];
        int end = row_ptr[ndc + 1];

        bf16x4 sv = *(const bf16x4*)(P + (size_t)ndc * 64 + fl * 4);
        float a0 = (float)sv[0], a1 = (float)sv[1], a2 = (float)sv[2], a3 = (float)sv[3];
        float c0 = 0.f, c1 = 0.f, c2 = 0.f, c3 = 0.f;

        int e = beg;
        if ((e & 1) && e < end) {                 // align to int4
            int2 m = meta[e];
            bf16x4 p = *(const bf16x4*)(P + (size_t)m.x * 64 + fl * 4);
            float w = __int_as_float(m.y);
            a0 = fmaf(w, (float)p[0], a0);
            a1 = fmaf(w, (float)p[1], a1);
            a2 = fmaf(w, (float)p[2], a2);
            a3 = fmaf(w, (float)p[3], a3);
            ++e;
        }
        for (; e + 3 < end; e += 4) {
            int4 A = *(const int4*)&meta[e];
            int4 B = *(const int4*)&meta[e + 2];
            bf16x4 p0 = *(const bf16x4*)(P + (size_t)A.x * 64 + fl * 4);
            bf16x4 p1 = *(const bf16x4*)(P + (size_t)A.z * 64 + fl * 4);
            bf16x4 p2 = *(const bf16x4*)(P + (size_t)B.x * 64 + fl * 4);
            bf16x4 p3 = *(const bf16x4*)(P + (size_t)B.z * 64 + fl * 4);
            float w0 = __int_as_float(A.y);
            float w1 = __int_as_float(A.w);
            float w2 = __int_as_float(B.y);
            float w3 = __int_as_float(B.w);
            a0 = fmaf(w0, (float)p0[0], a0);
            a1 = fmaf(w0, (float)p0[1], a1);
            a2 = fmaf(w0, (float)p0[2], a2);
            a3 = fmaf(w0, (float)p0[3], a3);
            c0 = fmaf(w1, (float)p1[0], c0);
            c1 = fmaf(w1, (float)p1[1], c1);
            c2 = fmaf(w1, (float)p1[2], c2);
            c3 = fmaf(w1, (float)p1[3], c3);
            a0 = fmaf(w2, (float)p2[0], a0);
            a1 = fmaf(w2, (float)p2[1], a1);
            a2 = fmaf(w2, (float)p2[2], a2);
            a3 = fmaf(w2, (float)p2[3], a3);
            c0 = fmaf(w3, (float)p3[0], c0);
            c1 = fmaf(w3, (float)p3[1], c1);
            c2 = fmaf(w3, (float)p3[2], c2);
            c3 = fmaf(w3, (float)p3[3], c3);
        }
        if (e + 1 < end) {
            int4 A = *(const int4*)&meta[e];
            bf16x4 p0 = *(const bf16x4*)(P + (size_t)A.x * 64 + fl * 4);
            bf16x4 p1 = *(const bf16x4*)(P + (size_t)A.z * 64 + fl * 4);
            float w0 = __int_as_float(A.y);
            float w1 = __int_as_float(A.w);
            a0 = fmaf(w0, (float)p0[0], a0);
            a1 = fmaf(w0, (float)p0[1], a1);
            a2 = fmaf(w0, (float)p0[2], a2);
            a3 = fmaf(w0, (float)p0[3], a3);
            c0 = fmaf(w1, (float)p1[0], c0);
            c1 = fmaf(w1, (float)p1[1], c1);
            c2 = fmaf(w1, (float)p1[2], c2);
            c3 = fmaf(w1, (float)p1[3], c3);
            e += 2;
        }
        if (e < end) {
            int2 m = meta[e];
            bf16x4 p = *(const bf16x4*)(P + (size_t)m.x * 64 + fl * 4);
            float w = __int_as_float(m.y);
            a0 = fmaf(w, (float)p[0], a0);
            a1 = fmaf(w, (float)p[1], a1);
            a2 = fmaf(w, (float)p[2], a2);
            a3 = fmaf(w, (float)p[3], a3);
        }
        a0 += c0; a1 += c1; a2 += c2; a3 += c3;

        float dn = dinv[ndc];
        a0 = fmaf(dn, a0, bv.x);
        a1 = fmaf(dn, a1, bv.y);
        a2 = fmaf(dn, a2, bv.z);
        a3 = fmaf(dn, a3, bv.w);

        float ss = a0 * a0 + a1 * a1 + a2 * a2 + a3 * a3;
        ss += __shfl_xor(ss, 1, 64);
        ss += __shfl_xor(ss, 2, 64);
        ss += __shfl_xor(ss, 4, 64);
        ss += __shfl_xor(ss, 8, 64);
        float inv = 1.0f / fmaxf(sqrtf(ss), 1e-12f);
        a0 = fmaxf(a0 * inv, 0.f);
        a1 = fmaxf(a1 * inv, 0.f);
        a2 = fmaxf(a2 * inv, 0.f);
        a3 = fmaxf(a3 * inv, 0.f);

        if (act) {
            if (F32OUT) {
                float4 o = {a0, a1, a2, a3};
                *(float4*)(Qf + (size_t)nd * 64 + fl * 4) = o;
            } else {
                bf16x4 o;
                o[0] = (bf16_t)a0; o[1] = (bf16_t)a1;
                o[2] = (bf16_t)a2; o[3] = (bf16_t)a3;
                *(bf16x4*)(Qb + (size_t)nd * 64 + fl * 4) = o;
            }
        }
    }
}

// ---------------- segmented pool (batch sorted) ----------------

__global__ void k_starts(const int* __restrict__ batch, int* __restrict__ starts,
                         int N, int G) {
    int g = blockIdx.x * blockDim.x + threadIdx.x;
    if (g > G) return;
    int lo = 0, hi = N;
    while (lo < hi) {
        int mid = (lo + hi) >> 1;
        if (batch[mid] < g) lo = mid + 1; else hi = mid;
    }
    starts[g] = lo;
}

__global__ void k_pool(const float* __restrict__ Q, const int* __restrict__ starts,
                       float* __restrict__ pooled, int G) {
    int lane = threadIdx.x & 63;
    int w = blockIdx.x * (blockDim.x >> 6) + (threadIdx.x >> 6);
    if (w >= G) return;
    float acc = 0.f;
    int end = starts[w + 1];
    for (int i = starts[w]; i < end; ++i) acc += Q[(size_t)i * 64 + lane];
    pooled[(size_t)w * 64 + lane] = acc;
}

// ---------------- per-graph MLP + log_softmax ----------------

__global__ void k_mlp(const float* __restrict__ pooled,
                      const float* __restrict__ fc1w, const float* __restrict__ fc1b,
                      const float* __restrict__ fc2w, const float* __restrict__ fc2b,
                      float* __restrict__ out, int G) {
    __shared__ float sp[64];
    __shared__ float sz[64];
    __shared__ float sl[10];
    __shared__ float slse;
    int g = blockIdx.x;
    int t = threadIdx.x;
    if (g >= G) return;
    sp[t] = pooled[(size_t)g * 64 + t];
    __syncthreads();
    float acc = fc1b[t];
#pragma unroll
    for (int k = 0; k < 64; ++k) acc += sp[k] * fc1w[k * 64 + t];
    sz[t] = fmaxf(acc, 0.f);
    __syncthreads();
    if (t < 10) {
        float a = fc2b[t];
#pragma unroll
        for (int j = 0; j < 64; ++j) a += sz[j] * fc2w[j * 10 + t];
        sl[t] = a;
    }
    __syncthreads();
    if (t == 0) {
        float m = sl[0];
        for (int c = 1; c < 10; ++c) m = fmaxf(m, sl[c]);
        float s = 0.f;
        for (int c = 0; c < 10; ++c) s += expf(sl[c] - m);
        slse = m + logf(s);
    }
    __syncthreads();
    if (t < 10) out[(size_t)g * 10 + t] = sl[t] - slse;
}

// ---------------- launch ----------------

extern "C" void kernel_launch(void* const* d_in, const int* in_sizes, int n_in,
                              void* d_out, int out_size, void* d_ws, size_t ws_size,
                              hipStream_t stream) {
    const float* x     = (const float*)d_in[0];
    const int*   ei    = (const int*)d_in[1];
    const int*   batch = (const int*)d_in[2];
    const float* ew    = (const float*)d_in[3];
    const float* W1 = (const float*)d_in[4];
    const float* b1 = (const float*)d_in[5];
    const float* W2 = (const float*)d_in[6];
    const float* b2 = (const float*)d_in[7];
    const float* W3 = (const float*)d_in[8];
    const float* b3 = (const float*)d_in[9];
    const float* fc1w = (const float*)d_in[10];
    const float* fc1b = (const float*)d_in[11];
    const float* fc2w = (const float*)d_in[12];
    const float* fc2b = (const float*)d_in[13];
    float* out = (float*)d_out;

    const int N = in_sizes[0] / 128;   // 100000 (multiple of 16)
    const int E = in_sizes[1] / 2;     // 3200000
    const int G = out_size / 10;       // 512
    const int NB = (N + 127) / 128;    // 782 buckets (<=1024)

    // workspace (256B-aligned chunks)
    char* wp = (char*)d_ws;
    auto alloc = [&](size_t bytes) {
        char* p = wp;
        wp += (bytes + 255) & ~(size_t)255;
        return p;
    };
    size_t qbytes = (size_t)N * 64 * 4;
    size_t rbytes = (size_t)E * 8;
    // Q region double-duty: Pass B/C records first, then conv outputs (records dead by then)
    char*   Qreg    = alloc(qbytes > rbytes ? qbytes : rbytes);
    float*  Qf      = (float*)Qreg;
    bf16_t* Qb      = (bf16_t*)Qreg;
    int2*   rec     = (int2*)Qreg;
    bf16_t* P       = (bf16_t*)alloc((size_t)N * 64 * 2);
    int2*   meta    = (int2*) alloc((size_t)E * 8);
    int*    row_ptr = (int*)  alloc((size_t)(N + 1) * 4);
    float*  dinv    = (float*)alloc((size_t)N * 4);
    float*  pooled  = (float*)alloc((size_t)G * 64 * 4);
    int*    starts  = (int*)  alloc((size_t)(G + 1) * 4);
    int*    btot    = (int*)  alloc((size_t)NB * 4);
    int*    bstart  = (int*)  alloc((size_t)(NB + 1) * 4);
    int*    bcur    = (int*)  alloc((size_t)NB * 4);

    dim3 blk(256);
    dim3 g1024(1024);
    const int ntiles = N / 16;                         // 6250
    const int nblkB  = (E + BTILE - 1) / BTILE;        // 782
    const int nquads = (N + 3) / 4;                    // 25000
    dim3 gconv((nquads + 3) / 4);                      // 6250 blocks, 1 quad/wave

    // CSR build: bucket histogram -> scan -> bin -> per-bucket sort (+dinv, row_ptr)
    k_fill_i<<<dim3(64), blk, 0, stream>>>(btot, 0, NB);
    k_bucket_hist<<<dim3(256), blk, 0, stream>>>(ei + E, E, NB, btot);
    k_bucket_scan<<<dim3(1), dim3(1024), 0, stream>>>(btot, bstart, bcur, NB);
    k_passB<<<dim3(nblkB), dim3(512), 0, stream>>>(ei, ew, bstart, bcur, rec, E, NB);
    k_passC<<<dim3(NB), blk, 0, stream>>>(rec, bstart, row_ptr, dinv, meta, N, E);
    k_starts<<<dim3(4), blk, 0, stream>>>(batch, starts, N, G);

    // conv1 (K=128, f32 A)   [rec region is dead from here on; Q reuses it]
    k_gemm_mfma<128, true><<<g1024, blk, 0, stream>>>(x, W1, dinv, P, ntiles);
    k_conv4<false><<<gconv, blk, 0, stream>>>(P, row_ptr, meta, dinv, b1, Qb, nullptr, N);
    // conv2 (K=64, bf16 A)
    k_gemm_mfma<64, false><<<g1024, blk, 0, stream>>>(Qb, W2, dinv, P, ntiles);
    k_conv4<false><<<gconv, blk, 0, stream>>>(P, row_ptr, meta, dinv, b2, Qb, nullptr, N);
    // conv3 (K=64, bf16 A, f32 node output for pooling)
    k_gemm_mfma<64, false><<<g1024, blk, 0, stream>>>(Qb, W3, dinv, P, ntiles);
    k_conv4<true><<<gconv, blk, 0, stream>>>(P, row_ptr, meta, dinv, b3, nullptr, Qf, N);

    // pool + MLP
    k_pool<<<dim3((G * 64 + 255) / 256), blk, 0, stream>>>(Qf, starts, pooled, G);
    k_mlp<<<dim3(G), dim3(64), 0, stream>>>(pooled, fc1w, fc1b, fc2w, fc2b, out, G);
}

// Round 8
// 418.362 us; speedup vs baseline: 5.9629x; 1.0964x over previous
//
#include <hip/hip_runtime.h>
#include <math.h>

typedef __bf16 bf16_t;
typedef __attribute__((ext_vector_type(4))) __bf16 bf16x4;
typedef __attribute__((ext_vector_type(8))) __bf16 bf16x8;
typedef __attribute__((ext_vector_type(4))) float f32x4;

#define BTILE 8192      // edges per passB tile
#define BSH   9         // bucket shift: 512 nodes per bucket
#define CAP   18432     // record capacity per bucket (mean 16384 + 16 sigma)

// ---------------- fills ----------------

__global__ void k_fill_i(int* __restrict__ p, int v, int n) {
    int i = blockIdx.x * blockDim.x + threadIdx.x;
    int s = gridDim.x * blockDim.x;
    for (; i < n; i += s) p[i] = v;
}

// ---------------- Pass B: bin edges into capacity-padded buckets ----------------
// record.x = (dst&511)<<17 | src  (src < 2^17), record.y = ew bits
// No pre-histogram: bucket b's region is rec[b*CAP ...]; one global atomic per
// (tile,bucket) reserves a run; within-tile ranks from LDS atomics (registers).

__global__ __launch_bounds__(512) void k_passB(const int* __restrict__ ei,
        const float* __restrict__ ew, int* __restrict__ bcur,
        int2* __restrict__ rec, int E, int NB) {
    __shared__ int lhist[256];
    __shared__ int base[256];
    const int* dstp = ei + E;
    int tile0 = blockIdx.x * BTILE;
    int t = threadIdx.x;
    if (t < 256) lhist[t] = 0;
    __syncthreads();
    int rank[BTILE / 512];
#pragma unroll
    for (int j = 0; j < BTILE / 512; ++j) {
        int e = tile0 + j * 512 + t;
        if (e < E) rank[j] = atomicAdd(&lhist[dstp[e] >> BSH], 1);
    }
    __syncthreads();
    if (t < NB) {
        int c = lhist[t];
        base[t] = c ? atomicAdd(&bcur[t], c) : 0;
    }
    __syncthreads();
#pragma unroll
    for (int j = 0; j < BTILE / 512; ++j) {
        int e = tile0 + j * 512 + t;
        if (e < E) {
            int d = dstp[e];
            int b = d >> BSH;
            rec[(size_t)b * CAP + base[b] + rank[j]] =
                make_int2(((d & 511) << 17) | ei[e], __float_as_int(ew[e]));
        }
    }
}

// ---------------- Pass C: per-bucket counting sort -> meta, rbeg/rend, dinv ----

__global__ __launch_bounds__(1024) void k_passC(const int2* __restrict__ rec,
        const int* __restrict__ bcur, int* __restrict__ rbeg, int* __restrict__ rend,
        float* __restrict__ dinv, int2* __restrict__ meta, int N) {
    __shared__ int   nh[512];
    __shared__ float sw[512];
    __shared__ int   offs[512];
    __shared__ int   cur[512];
    __shared__ int   scn[512];
    int b = blockIdx.x, t = threadIdx.x;
    if (t < 512) { nh[t] = 0; sw[t] = 0.f; cur[t] = 0; }
    __syncthreads();
    int len = bcur[b];
    size_t rs = (size_t)b * CAP;
    for (int i = t; i < len; i += 1024) {
        int2 r = rec[rs + i];
        int dl = r.x >> 17;
        atomicAdd(&nh[dl], 1);
        atomicAdd(&sw[dl], __int_as_float(r.y));
    }
    __syncthreads();
    if (t < 512) scn[t] = nh[t];
    __syncthreads();
    for (int off = 1; off < 512; off <<= 1) {
        int v = (t >= off && t < 512) ? scn[t - off] : 0;
        __syncthreads();
        if (t < 512) scn[t] += v;
        __syncthreads();
    }
    if (t < 512) {
        offs[t] = scn[t] - nh[t];
        int node = (b << BSH) + t;
        if (node < N) {
            int rb = (int)rs + offs[t];
            rbeg[node] = rb;
            rend[node] = rb + nh[t];
            dinv[node] = rsqrtf(1.f + sw[t]);
        }
    }
    __syncthreads();
    for (int i = t; i < len; i += 1024) {
        int2 r = rec[rs + i];
        int dl = r.x >> 17;
        int pos = atomicAdd(&cur[dl], 1);
        meta[rs + offs[dl] + pos] = make_int2(r.x & 0x1FFFF, r.y);
    }
}

// ---------------- MFMA GEMM: out[n][f] = dinv[n] * (X[n][:] @ W[:][f]) ----------------

template <int K, bool A_F32>
__global__ __launch_bounds__(256) void k_gemm_mfma(
        const void* __restrict__ Xv, const float* __restrict__ W,
        const float* __restrict__ dinv, bf16_t* __restrict__ outb, int ntiles) {
    __shared__ bf16_t sWt[64 * K];              // transposed W: sWt[c*K + k]
    for (int idx = threadIdx.x; idx < K * 64; idx += blockDim.x) {
        int k = idx >> 6, c = idx & 63;
        sWt[c * K + k] = (bf16_t)W[idx];
    }
    __syncthreads();

    int lane = threadIdx.x & 63;
    int wid  = threadIdx.x >> 6;
    int colbase = wid * 16;
    int lm = lane & 15;
    int lk = lane >> 4;

    bf16x8 bfrag[K / 32];
#pragma unroll
    for (int ks = 0; ks < K / 32; ++ks)
        bfrag[ks] = *(const bf16x8*)&sWt[(colbase + lm) * K + ks * 32 + lk * 8];

    const float*  Xf = (const float*)Xv;
    const bf16_t* Xb = (const bf16_t*)Xv;

    for (int t = blockIdx.x; t < ntiles; t += gridDim.x) {
        f32x4 acc = {0.f, 0.f, 0.f, 0.f};
        size_t rowoff = (size_t)(t * 16 + lm) * K + lk * 8;
#pragma unroll
        for (int ks = 0; ks < K / 32; ++ks) {
            bf16x8 afrag;
            if (A_F32) {
                float4 v0 = *(const float4*)(Xf + rowoff + ks * 32);
                float4 v1 = *(const float4*)(Xf + rowoff + ks * 32 + 4);
                afrag[0] = (bf16_t)v0.x; afrag[1] = (bf16_t)v0.y;
                afrag[2] = (bf16_t)v0.z; afrag[3] = (bf16_t)v0.w;
                afrag[4] = (bf16_t)v1.x; afrag[5] = (bf16_t)v1.y;
                afrag[6] = (bf16_t)v1.z; afrag[7] = (bf16_t)v1.w;
            } else {
                afrag = *(const bf16x8*)(Xb + rowoff + ks * 32);
            }
            acc = __builtin_amdgcn_mfma_f32_16x16x32_bf16(afrag, bfrag[ks], acc, 0, 0, 0);
        }
#pragma unroll
        for (int r = 0; r < 4; ++r) {
            int row = t * 16 + lk * 4 + r;
            outb[(size_t)row * 64 + colbase + lm] = (bf16_t)(acc[r] * dinv[row]);
        }
    }
}

// ---------------- fused gather-conv, 4 nodes per wave, 4 edges/iter ----------------

template <bool F32OUT>
__global__ __launch_bounds__(256) void k_conv4(
        const bf16_t* __restrict__ P, const int* __restrict__ rbeg,
        const int* __restrict__ rend,
        const int2* __restrict__ meta, const float* __restrict__ dinv,
        const float* __restrict__ b, bf16_t* __restrict__ Qb,
        float* __restrict__ Qf, int n_nodes) {
    int lane = threadIdx.x & 63;
    int g  = lane >> 4;
    int fl = lane & 15;
    int wave  = blockIdx.x * (blockDim.x >> 6) + (threadIdx.x >> 6);
    int nwave = gridDim.x * (blockDim.x >> 6);
    int nquads = (n_nodes + 3) >> 2;

    float4 bv = *(const float4*)(b + fl * 4);

    for (int q = wave; q < nquads; q += nwave) {
        int nd = q * 4 + g;
        bool act = nd < n_nodes;
        int ndc = act ? nd : 0;

        int beg = rbeg[ndc];
        int end = rend[ndc];

        bf16x4 sv = *(const bf16x4*)(P + (size_t)ndc * 64 + fl * 4);
        float a0 = (float)sv[0], a1 = (float)sv[1], a2 = (float)sv[2], a3 = (float)sv[3];
        float c0 = 0.f, c1 = 0.f, c2 = 0.f, c3 = 0.f;

        int e = beg;
        if ((e & 1) && e < end) {                 // align to int4
            int2 m = meta[e];
            bf16x4 p = *(const bf16x4*)(P + (size_t)m.x * 64 + fl * 4);
            float w = __int_as_float(m.y);
            a0 = fmaf(w, (float)p[0], a0);
            a1 = fmaf(w, (float)p[1], a1);
            a2 = fmaf(w, (float)p[2], a2);
            a3 = fmaf(w, (float)p[3], a3);
            ++e;
        }
        for (; e + 3 < end; e += 4) {
            int4 A = *(const int4*)&meta[e];
            int4 B = *(const int4*)&meta[e + 2];
            bf16x4 p0 = *(const bf16x4*)(P + (size_t)A.x * 64 + fl * 4);
            bf16x4 p1 = *(const bf16x4*)(P + (size_t)A.z * 64 + fl * 4);
            bf16x4 p2 = *(const bf16x4*)(P + (size_t)B.x * 64 + fl * 4);
            bf16x4 p3 = *(const bf16x4*)(P + (size_t)B.z * 64 + fl * 4);
            float w0 = __int_as_float(A.y);
            float w1 = __int_as_float(A.w);
            float w2 = __int_as_float(B.y);
            float w3 = __int_as_float(B.w);
            a0 = fmaf(w0, (float)p0[0], a0);
            a1 = fmaf(w0, (float)p0[1], a1);
            a2 = fmaf(w0, (float)p0[2], a2);
            a3 = fmaf(w0, (float)p0[3], a3);
            c0 = fmaf(w1, (float)p1[0], c0);
            c1 = fmaf(w1, (float)p1[1], c1);
            c2 = fmaf(w1, (float)p1[2], c2);
            c3 = fmaf(w1, (float)p1[3], c3);
            a0 = fmaf(w2, (float)p2[0], a0);
            a1 = fmaf(w2, (float)p2[1], a1);
            a2 = fmaf(w2, (float)p2[2], a2);
            a3 = fmaf(w2, (float)p2[3], a3);
            c0 = fmaf(w3, (float)p3[0], c0);
            c1 = fmaf(w3, (float)p3[1], c1);
            c2 = fmaf(w3, (float)p3[2], c2);
            c3 = fmaf(w3, (float)p3[3], c3);
        }
        if (e + 1 < end) {
            int4 A = *(const int4*)&meta[e];
            bf16x4 p0 = *(const bf16x4*)(P + (size_t)A.x * 64 + fl * 4);
            bf16x4 p1 = *(const bf16x4*)(P + (size_t)A.z * 64 + fl * 4);
            float w0 = __int_as_float(A.y);
            float w1 = __int_as_float(A.w);
            a0 = fmaf(w0, (float)p0[0], a0);
            a1 = fmaf(w0, (float)p0[1], a1);
            a2 = fmaf(w0, (float)p0[2], a2);
            a3 = fmaf(w0, (float)p0[3], a3);
            c0 = fmaf(w1, (float)p1[0], c0);
            c1 = fmaf(w1, (float)p1[1], c1);
            c2 = fmaf(w1, (float)p1[2], c2);
            c3 = fmaf(w1, (float)p1[3], c3);
            e += 2;
        }
        if (e < end) {
            int2 m = meta[e];
            bf16x4 p = *(const bf16x4*)(P + (size_t)m.x * 64 + fl * 4);
            float w = __int_as_float(m.y);
            a0 = fmaf(w, (float)p[0], a0);
            a1 = fmaf(w, (float)p[1], a1);
            a2 = fmaf(w, (float)p[2], a2);
            a3 = fmaf(w, (float)p[3], a3);
        }
        a0 += c0; a1 += c1; a2 += c2; a3 += c3;

        float dn = dinv[ndc];
        a0 = fmaf(dn, a0, bv.x);
        a1 = fmaf(dn, a1, bv.y);
        a2 = fmaf(dn, a2, bv.z);
        a3 = fmaf(dn, a3, bv.w);

        float ss = a0 * a0 + a1 * a1 + a2 * a2 + a3 * a3;
        ss += __shfl_xor(ss, 1, 64);
        ss += __shfl_xor(ss, 2, 64);
        ss += __shfl_xor(ss, 4, 64);
        ss += __shfl_xor(ss, 8, 64);
        float inv = 1.0f / fmaxf(sqrtf(ss), 1e-12f);
        a0 = fmaxf(a0 * inv, 0.f);
        a1 = fmaxf(a1 * inv, 0.f);
        a2 = fmaxf(a2 * inv, 0.f);
        a3 = fmaxf(a3 * inv, 0.f);

        if (act) {
            if (F32OUT) {
                float4 o = {a0, a1, a2, a3};
                *(float4*)(Qf + (size_t)nd * 64 + fl * 4) = o;
            } else {
                bf16x4 o;
                o[0] = (bf16_t)a0; o[1] = (bf16_t)a1;
                o[2] = (bf16_t)a2; o[3] = (bf16_t)a3;
                *(bf16x4*)(Qb + (size_t)nd * 64 + fl * 4) = o;
            }
        }
    }
}

// ---------------- segmented pool (batch sorted) ----------------

__global__ void k_starts(const int* __restrict__ batch, int* __restrict__ starts,
                         int N, int G) {
    int g = blockIdx.x * blockDim.x + threadIdx.x;
    if (g > G) return;
    int lo = 0, hi = N;
    while (lo < hi) {
        int mid = (lo + hi) >> 1;
        if (batch[mid] < g) lo = mid + 1; else hi = mid;
    }
    starts[g] = lo;
}

__global__ void k_pool(const float* __restrict__ Q, const int* __restrict__ starts,
                       float* __restrict__ pooled, int G) {
    int lane = threadIdx.x & 63;
    int w = blockIdx.x * (blockDim.x >> 6) + (threadIdx.x >> 6);
    if (w >= G) return;
    float acc = 0.f;
    int end = starts[w + 1];
    for (int i = starts[w]; i < end; ++i) acc += Q[(size_t)i * 64 + lane];
    pooled[(size_t)w * 64 + lane] = acc;
}

// ---------------- per-graph MLP + log_softmax ----------------

__global__ void k_mlp(const float* __restrict__ pooled,
                      const float* __restrict__ fc1w, const float* __restrict__ fc1b,
                      const float* __restrict__ fc2w, const float* __restrict__ fc2b,
                      float* __restrict__ out, int G) {
    __shared__ float sp[64];
    __shared__ float sz[64];
    __shared__ float sl[10];
    __shared__ float slse;
    int g = blockIdx.x;
    int t = threadIdx.x;
    if (g >= G) return;
    sp[t] = pooled[(size_t)g * 64 + t];
    __syncthreads();
    float acc = fc1b[t];
#pragma unroll
    for (int k = 0; k < 64; ++k) acc += sp[k] * fc1w[k * 64 + t];
    sz[t] = fmaxf(acc, 0.f);
    __syncthreads();
    if (t < 10) {
        float a = fc2b[t];
#pragma unroll
        for (int j = 0; j < 64; ++j) a += sz[j] * fc2w[j * 10 + t];
        sl[t] = a;
    }
    __syncthreads();
    if (t == 0) {
        float m = sl[0];
        for (int c = 1; c < 10; ++c) m = fmaxf(m, sl[c]);
        float s = 0.f;
        for (int c = 0; c < 10; ++c) s += expf(sl[c] - m);
        slse = m + logf(s);
    }
    __syncthreads();
    if (t < 10) out[(size_t)g * 10 + t] = sl[t] - slse;
}

// ---------------- launch ----------------

extern "C" void kernel_launch(void* const* d_in, const int* in_sizes, int n_in,
                              void* d_out, int out_size, void* d_ws, size_t ws_size,
                              hipStream_t stream) {
    const float* x     = (const float*)d_in[0];
    const int*   ei    = (const int*)d_in[1];
    const int*   batch = (const int*)d_in[2];
    const float* ew    = (const float*)d_in[3];
    const float* W1 = (const float*)d_in[4];
    const float* b1 = (const float*)d_in[5];
    const float* W2 = (const float*)d_in[6];
    const float* b2 = (const float*)d_in[7];
    const float* W3 = (const float*)d_in[8];
    const float* b3 = (const float*)d_in[9];
    const float* fc1w = (const float*)d_in[10];
    const float* fc1b = (const float*)d_in[11];
    const float* fc2w = (const float*)d_in[12];
    const float* fc2b = (const float*)d_in[13];
    float* out = (float*)d_out;

    const int N = in_sizes[0] / 128;   // 100000 (multiple of 16)
    const int E = in_sizes[1] / 2;     // 3200000
    const int G = out_size / 10;       // 512
    const int NB = (N + (1 << BSH) - 1) >> BSH;   // 196 buckets of 512 nodes

    // workspace (256B-aligned chunks)
    char* wp = (char*)d_ws;
    auto alloc = [&](size_t bytes) {
        char* p = wp;
        wp += (bytes + 255) & ~(size_t)255;
        return p;
    };
    size_t qbytes = (size_t)N * 64 * 4;
    size_t rbytes = (size_t)NB * CAP * 8;
    // Q region double-duty: padded rec first, then conv outputs (rec dead by then)
    char*   Qreg    = alloc(qbytes > rbytes ? qbytes : rbytes);
    float*  Qf      = (float*)Qreg;
    bf16_t* Qb      = (bf16_t*)Qreg;
    int2*   rec     = (int2*)Qreg;
    bf16_t* P       = (bf16_t*)alloc((size_t)N * 64 * 2);
    int2*   meta    = (int2*) alloc(rbytes);          // padded, indexed via rbeg/rend
    int*    rbeg    = (int*)  alloc((size_t)N * 4);
    int*    rend    = (int*)  alloc((size_t)N * 4);
    float*  dinv    = (float*)alloc((size_t)N * 4);
    float*  pooled  = (float*)alloc((size_t)G * 64 * 4);
    int*    starts  = (int*)  alloc((size_t)(G + 1) * 4);
    int*    bcur    = (int*)  alloc((size_t)NB * 4);

    dim3 blk(256);
    dim3 g1024(1024);
    const int ntiles = N / 16;                         // 6250
    const int nblkB  = (E + BTILE - 1) / BTILE;        // 391
    const int nquads = (N + 3) / 4;                    // 25000
    dim3 gconv((nquads + 3) / 4);                      // 6250 blocks, 1 quad/wave

    // CSR build: bin into padded buckets -> per-bucket sort (+dinv, rbeg/rend)
    k_fill_i<<<dim3(1), blk, 0, stream>>>(bcur, 0, NB);
    k_passB<<<dim3(nblkB), dim3(512), 0, stream>>>(ei, ew, bcur, rec, E, NB);
    k_passC<<<dim3(NB), dim3(1024), 0, stream>>>(rec, bcur, rbeg, rend, dinv, meta, N);
    k_starts<<<dim3(4), blk, 0, stream>>>(batch, starts, N, G);

    // conv1 (K=128, f32 A)   [rec region is dead from here on; Q reuses it]
    k_gemm_mfma<128, true><<<g1024, blk, 0, stream>>>(x, W1, dinv, P, ntiles);
    k_conv4<false><<<gconv, blk, 0, stream>>>(P, rbeg, rend, meta, dinv, b1, Qb, nullptr, N);
    // conv2 (K=64, bf16 A)
    k_gemm_mfma<64, false><<<g1024, blk, 0, stream>>>(Qb, W2, dinv, P, ntiles);
    k_conv4<false><<<gconv, blk, 0, stream>>>(P, rbeg, rend, meta, dinv, b2, Qb, nullptr, N);
    // conv3 (K=64, bf16 A, f32 node output for pooling)
    k_gemm_mfma<64, false><<<g1024, blk, 0, stream>>>(Qb, W3, dinv, P, ntiles);
    k_conv4<true><<<gconv, blk, 0, stream>>>(P, rbeg, rend, meta, dinv, b3, nullptr, Qf, N);

    // pool + MLP
    k_pool<<<dim3((G * 64 + 255) / 256), blk, 0, stream>>>(Qf, starts, pooled, G);
    k_mlp<<<dim3(G), dim3(64), 0, stream>>>(pooled, fc1w, fc1b, fc2w, fc2b, out, G);
}

// Round 9
// 358.769 us; speedup vs baseline: 6.9534x; 1.1661x over previous
//
#include <hip/hip_runtime.h>
#include <math.h>

typedef __bf16 bf16_t;
typedef __attribute__((ext_vector_type(4))) __bf16 bf16x4;
typedef __attribute__((ext_vector_type(8))) __bf16 bf16x8;
typedef __attribute__((ext_vector_type(4))) float f32x4;

#define BTILE 8192      // edges per passB tile
#define BSH   9         // bucket shift: 512 nodes per bucket
#define CAP   18432     // record capacity per bucket (mean 16384 + 16 sigma)

// ---------------- fills ----------------

__global__ void k_fill_i(int* __restrict__ p, int v, int n) {
    int i = blockIdx.x * blockDim.x + threadIdx.x;
    int s = gridDim.x * blockDim.x;
    for (; i < n; i += s) p[i] = v;
}

// ---------------- Pass B: bin edges into capacity-padded buckets ----------------
// record.x = (dst&511)<<17 | src  (src < 2^17), record.y = ew bits

__global__ __launch_bounds__(512) void k_passB(const int* __restrict__ ei,
        const float* __restrict__ ew, int* __restrict__ bcur,
        int2* __restrict__ rec, int E, int NB) {
    __shared__ int lhist[256];
    __shared__ int base[256];
    const int* dstp = ei + E;
    int tile0 = blockIdx.x * BTILE;
    int t = threadIdx.x;
    if (t < 256) lhist[t] = 0;
    __syncthreads();
    int rank[BTILE / 512];
#pragma unroll
    for (int j = 0; j < BTILE / 512; ++j) {
        int e = tile0 + j * 512 + t;
        if (e < E) rank[j] = atomicAdd(&lhist[dstp[e] >> BSH], 1);
    }
    __syncthreads();
    if (t < NB) {
        int c = lhist[t];
        base[t] = c ? atomicAdd(&bcur[t], c) : 0;
    }
    __syncthreads();
#pragma unroll
    for (int j = 0; j < BTILE / 512; ++j) {
        int e = tile0 + j * 512 + t;
        if (e < E) {
            int d = dstp[e];
            int b = d >> BSH;
            rec[(size_t)b * CAP + base[b] + rank[j]] =
                make_int2(((d & 511) << 17) | ei[e], __float_as_int(ew[e]));
        }
    }
}

// ---------------- Pass C: per-bucket counting sort -> meta, rbeg/rend, dinv ----

__global__ __launch_bounds__(1024) void k_passC(const int2* __restrict__ rec,
        const int* __restrict__ bcur, int* __restrict__ rbeg, int* __restrict__ rend,
        float* __restrict__ dinv, int2* __restrict__ meta, int N) {
    __shared__ int   nh[512];
    __shared__ float sw[512];
    __shared__ int   offs[512];
    __shared__ int   cur[512];
    __shared__ int   scn[512];
    int b = blockIdx.x, t = threadIdx.x;
    if (t < 512) { nh[t] = 0; sw[t] = 0.f; cur[t] = 0; }
    __syncthreads();
    int len = bcur[b];
    size_t rs = (size_t)b * CAP;
    for (int i = t; i < len; i += 1024) {
        int2 r = rec[rs + i];
        int dl = r.x >> 17;
        atomicAdd(&nh[dl], 1);
        atomicAdd(&sw[dl], __int_as_float(r.y));
    }
    __syncthreads();
    if (t < 512) scn[t] = nh[t];
    __syncthreads();
    for (int off = 1; off < 512; off <<= 1) {
        int v = (t >= off && t < 512) ? scn[t - off] : 0;
        __syncthreads();
        if (t < 512) scn[t] += v;
        __syncthreads();
    }
    if (t < 512) {
        offs[t] = scn[t] - nh[t];
        int node = (b << BSH) + t;
        if (node < N) {
            int rb = (int)rs + offs[t];
            rbeg[node] = rb;
            rend[node] = rb + nh[t];
            dinv[node] = rsqrtf(1.f + sw[t]);
        }
    }
    __syncthreads();
    for (int i = t; i < len; i += 1024) {
        int2 r = rec[rs + i];
        int dl = r.x >> 17;
        int pos = atomicAdd(&cur[dl], 1);
        meta[rs + offs[dl] + pos] = make_int2(r.x & 0x1FFFF, r.y);
    }
}

// ---------------- MFMA GEMM: out[n][f] = dinv[n] * (X[n][:] @ W[:][f]) ----------------

template <int K, bool A_F32>
__global__ __launch_bounds__(256) void k_gemm_mfma(
        const void* __restrict__ Xv, const float* __restrict__ W,
        const float* __restrict__ dinv, bf16_t* __restrict__ outb, int ntiles) {
    __shared__ bf16_t sWt[64 * K];              // transposed W: sWt[c*K + k]
    for (int idx = threadIdx.x; idx < K * 64; idx += blockDim.x) {
        int k = idx >> 6, c = idx & 63;
        sWt[c * K + k] = (bf16_t)W[idx];
    }
    __syncthreads();

    int lane = threadIdx.x & 63;
    int wid  = threadIdx.x >> 6;
    int colbase = wid * 16;
    int lm = lane & 15;
    int lk = lane >> 4;

    bf16x8 bfrag[K / 32];
#pragma unroll
    for (int ks = 0; ks < K / 32; ++ks)
        bfrag[ks] = *(const bf16x8*)&sWt[(colbase + lm) * K + ks * 32 + lk * 8];

    const float*  Xf = (const float*)Xv;
    const bf16_t* Xb = (const bf16_t*)Xv;

    for (int t = blockIdx.x; t < ntiles; t += gridDim.x) {
        f32x4 acc = {0.f, 0.f, 0.f, 0.f};
        size_t rowoff = (size_t)(t * 16 + lm) * K + lk * 8;
#pragma unroll
        for (int ks = 0; ks < K / 32; ++ks) {
            bf16x8 afrag;
            if (A_F32) {
                float4 v0 = *(const float4*)(Xf + rowoff + ks * 32);
                float4 v1 = *(const float4*)(Xf + rowoff + ks * 32 + 4);
                afrag[0] = (bf16_t)v0.x; afrag[1] = (bf16_t)v0.y;
                afrag[2] = (bf16_t)v0.z; afrag[3] = (bf16_t)v0.w;
                afrag[4] = (bf16_t)v1.x; afrag[5] = (bf16_t)v1.y;
                afrag[6] = (bf16_t)v1.z; afrag[7] = (bf16_t)v1.w;
            } else {
                afrag = *(const bf16x8*)(Xb + rowoff + ks * 32);
            }
            acc = __builtin_amdgcn_mfma_f32_16x16x32_bf16(afrag, bfrag[ks], acc, 0, 0, 0);
        }
#pragma unroll
        for (int r = 0; r < 4; ++r) {
            int row = t * 16 + lk * 4 + r;
            outb[(size_t)row * 64 + colbase + lm] = (bf16_t)(acc[r] * dinv[row]);
        }
    }
}

// ---------------- fused gather-conv, 4 nodes per wave, 4 edges/iter ----------------

template <bool F32OUT>
__global__ __launch_bounds__(256) void k_conv4(
        const bf16_t* __restrict__ P, const int* __restrict__ rbeg,
        const int* __restrict__ rend,
        const int2* __restrict__ meta, const float* __restrict__ dinv,
        const float* __restrict__ b, bf16_t* __restrict__ Qb,
        float* __restrict__ Qf, int n_nodes) {
    int lane = threadIdx.x & 63;
    int g  = lane >> 4;
    int fl = lane & 15;
    int wave  = blockIdx.x * (blockDim.x >> 6) + (threadIdx.x >> 6);
    int nwave = gridDim.x * (blockDim.x >> 6);
    int nquads = (n_nodes + 3) >> 2;

    float4 bv = *(const float4*)(b + fl * 4);

    for (int q = wave; q < nquads; q += nwave) {
        int nd = q * 4 + g;
        bool act = nd < n_nodes;
        int ndc = act ? nd : 0;

        int beg = rbeg[ndc];
        int end = rend[ndc];

        bf16x4 sv = *(const bf16x4*)(P + (size_t)ndc * 64 + fl * 4);
        float a0 = (float)sv[0], a1 = (float)sv[1], a2 = (float)sv[2], a3 = (float)sv[3];
        float c0 = 0.f, c1 = 0.f, c2 = 0.f, c3 = 0.f;

        int e = beg;
        if ((e & 1) && e < end) {                 // align to int4
            int2 m = meta[e];
            bf16x4 p = *(const bf16x4*)(P + (size_t)m.x * 64 + fl * 4);
            float w = __int_as_float(m.y);
            a0 = fmaf(w, (float)p[0], a0);
            a1 = fmaf(w, (float)p[1], a1);
            a2 = fmaf(w, (float)p[2], a2);
            a3 = fmaf(w, (float)p[3], a3);
            ++e;
        }
        for (; e + 3 < end; e += 4) {
            int4 A = *(const int4*)&meta[e];
            int4 B = *(const int4*)&meta[e + 2];
            bf16x4 p0 = *(const bf16x4*)(P + (size_t)A.x * 64 + fl * 4);
            bf16x4 p1 = *(const bf16x4*)(P + (size_t)A.z * 64 + fl * 4);
            bf16x4 p2 = *(const bf16x4*)(P + (size_t)B.x * 64 + fl * 4);
            bf16x4 p3 = *(const bf16x4*)(P + (size_t)B.z * 64 + fl * 4);
            float w0 = __int_as_float(A.y);
            float w1 = __int_as_float(A.w);
            float w2 = __int_as_float(B.y);
            float w3 = __int_as_float(B.w);
            a0 = fmaf(w0, (float)p0[0], a0);
            a1 = fmaf(w0, (float)p0[1], a1);
            a2 = fmaf(w0, (float)p0[2], a2);
            a3 = fmaf(w0, (float)p0[3], a3);
            c0 = fmaf(w1, (float)p1[0], c0);
            c1 = fmaf(w1, (float)p1[1], c1);
            c2 = fmaf(w1, (float)p1[2], c2);
            c3 = fmaf(w1, (float)p1[3], c3);
            a0 = fmaf(w2, (float)p2[0], a0);
            a1 = fmaf(w2, (float)p2[1], a1);
            a2 = fmaf(w2, (float)p2[2], a2);
            a3 = fmaf(w2, (float)p2[3], a3);
            c0 = fmaf(w3, (float)p3[0], c0);
            c1 = fmaf(w3, (float)p3[1], c1);
            c2 = fmaf(w3, (float)p3[2], c2);
            c3 = fmaf(w3, (float)p3[3], c3);
        }
        if (e + 1 < end) {
            int4 A = *(const int4*)&meta[e];
            bf16x4 p0 = *(const bf16x4*)(P + (size_t)A.x * 64 + fl * 4);
            bf16x4 p1 = *(const bf16x4*)(P + (size_t)A.z * 64 + fl * 4);
            float w0 = __int_as_float(A.y);
            float w1 = __int_as_float(A.w);
            a0 = fmaf(w0, (float)p0[0], a0);
            a1 = fmaf(w0, (float)p0[1], a1);
            a2 = fmaf(w0, (float)p0[2], a2);
            a3 = fmaf(w0, (float)p0[3], a3);
            c0 = fmaf(w1, (float)p1[0], c0);
            c1 = fmaf(w1, (float)p1[1], c1);
            c2 = fmaf(w1, (float)p1[2], c2);
            c3 = fmaf(w1, (float)p1[3], c3);
            e += 2;
        }
        if (e < end) {
            int2 m = meta[e];
            bf16x4 p = *(const bf16x4*)(P + (size_t)m.x * 64 + fl * 4);
            float w = __int_as_float(m.y);
            a0 = fmaf(w, (float)p[0], a0);
            a1 = fmaf(w, (float)p[1], a1);
            a2 = fmaf(w, (float)p[2], a2);
            a3 = fmaf(w, (float)p[3], a3);
        }
        a0 += c0; a1 += c1; a2 += c2; a3 += c3;

        float dn = dinv[ndc];
        a0 = fmaf(dn, a0, bv.x);
        a1 = fmaf(dn, a1, bv.y);
        a2 = fmaf(dn, a2, bv.z);
        a3 = fmaf(dn, a3, bv.w);

        float ss = a0 * a0 + a1 * a1 + a2 * a2 + a3 * a3;
        ss += __shfl_xor(ss, 1, 64);
        ss += __shfl_xor(ss, 2, 64);
        ss += __shfl_xor(ss, 4, 64);
        ss += __shfl_xor(ss, 8, 64);
        float inv = 1.0f / fmaxf(sqrtf(ss), 1e-12f);
        a0 = fmaxf(a0 * inv, 0.f);
        a1 = fmaxf(a1 * inv, 0.f);
        a2 = fmaxf(a2 * inv, 0.f);
        a3 = fmaxf(a3 * inv, 0.f);

        if (act) {
            if (F32OUT) {
                float4 o = {a0, a1, a2, a3};
                *(float4*)(Qf + (size_t)nd * 64 + fl * 4) = o;
            } else {
                bf16x4 o;
                o[0] = (bf16_t)a0; o[1] = (bf16_t)a1;
                o[2] = (bf16_t)a2; o[3] = (bf16_t)a3;
                *(bf16x4*)(Qb + (size_t)nd * 64 + fl * 4) = o;
            }
        }
    }
}

// ---------------- segmented pool (batch sorted) ----------------

__global__ void k_starts(const int* __restrict__ batch, int* __restrict__ starts,
                         int N, int G) {
    int g = blockIdx.x * blockDim.x + threadIdx.x;
    if (g > G) return;
    int lo = 0, hi = N;
    while (lo < hi) {
        int mid = (lo + hi) >> 1;
        if (batch[mid] < g) lo = mid + 1; else hi = mid;
    }
    starts[g] = lo;
}

// one 512-thread block per graph; t&15 = feature quad, t>>4 = row group (32-way)
__global__ __launch_bounds__(512) void k_pool(const float* __restrict__ Q,
        const int* __restrict__ starts, float* __restrict__ pooled, int G) {
    __shared__ float4 red[8][16];
    int g = blockIdx.x;
    int t = threadIdx.x;
    int fl = t & 15;
    int rg = t >> 4;          // 0..31
    int beg = starts[g], end = starts[g + 1];
    float4 acc = {0.f, 0.f, 0.f, 0.f};
    int i = beg + rg;
    for (; i + 32 < end; i += 64) {
        float4 v0 = *(const float4*)(Q + (size_t)i * 64 + fl * 4);
        float4 v1 = *(const float4*)(Q + (size_t)(i + 32) * 64 + fl * 4);
        acc.x += v0.x + v1.x; acc.y += v0.y + v1.y;
        acc.z += v0.z + v1.z; acc.w += v0.w + v1.w;
    }
    if (i < end) {
        float4 v = *(const float4*)(Q + (size_t)i * 64 + fl * 4);
        acc.x += v.x; acc.y += v.y; acc.z += v.z; acc.w += v.w;
    }
    // fold 4 row-groups within each wave (lanes differ in bits 4..5)
    acc.x += __shfl_xor(acc.x, 16, 64); acc.y += __shfl_xor(acc.y, 16, 64);
    acc.z += __shfl_xor(acc.z, 16, 64); acc.w += __shfl_xor(acc.w, 16, 64);
    acc.x += __shfl_xor(acc.x, 32, 64); acc.y += __shfl_xor(acc.y, 32, 64);
    acc.z += __shfl_xor(acc.z, 32, 64); acc.w += __shfl_xor(acc.w, 32, 64);
    int w = t >> 6;
    if ((t & 63) < 16) red[w][fl] = acc;
    __syncthreads();
    if (t < 16) {
        float4 s = red[0][t];
#pragma unroll
        for (int j = 1; j < 8; ++j) {
            float4 v = red[j][t];
            s.x += v.x; s.y += v.y; s.z += v.z; s.w += v.w;
        }
        *(float4*)(pooled + (size_t)g * 64 + t * 4) = s;
    }
}

// ---------------- per-graph MLP + log_softmax ----------------

__global__ void k_mlp(const float* __restrict__ pooled,
                      const float* __restrict__ fc1w, const float* __restrict__ fc1b,
                      const float* __restrict__ fc2w, const float* __restrict__ fc2b,
                      float* __restrict__ out, int G) {
    __shared__ float sp[64];
    __shared__ float sz[64];
    __shared__ float sl[10];
    __shared__ float slse;
    int g = blockIdx.x;
    int t = threadIdx.x;
    if (g >= G) return;
    sp[t] = pooled[(size_t)g * 64 + t];
    __syncthreads();
    float acc = fc1b[t];
#pragma unroll
    for (int k = 0; k < 64; ++k) acc += sp[k] * fc1w[k * 64 + t];
    sz[t] = fmaxf(acc, 0.f);
    __syncthreads();
    if (t < 10) {
        float a = fc2b[t];
#pragma unroll
        for (int j = 0; j < 64; ++j) a += sz[j] * fc2w[j * 10 + t];
        sl[t] = a;
    }
    __syncthreads();
    if (t == 0) {
        float m = sl[0];
        for (int c = 1; c < 10; ++c) m = fmaxf(m, sl[c]);
        float s = 0.f;
        for (int c = 0; c < 10; ++c) s += expf(sl[c] - m);
        slse = m + logf(s);
    }
    __syncthreads();
    if (t < 10) out[(size_t)g * 10 + t] = sl[t] - slse;
}

// ---------------- launch ----------------

extern "C" void kernel_launch(void* const* d_in, const int* in_sizes, int n_in,
                              void* d_out, int out_size, void* d_ws, size_t ws_size,
                              hipStream_t stream) {
    const float* x     = (const float*)d_in[0];
    const int*   ei    = (const int*)d_in[1];
    const int*   batch = (const int*)d_in[2];
    const float* ew    = (const float*)d_in[3];
    const float* W1 = (const float*)d_in[4];
    const float* b1 = (const float*)d_in[5];
    const float* W2 = (const float*)d_in[6];
    const float* b2 = (const float*)d_in[7];
    const float* W3 = (const float*)d_in[8];
    const float* b3 = (const float*)d_in[9];
    const float* fc1w = (const float*)d_in[10];
    const float* fc1b = (const float*)d_in[11];
    const float* fc2w = (const float*)d_in[12];
    const float* fc2b = (const float*)d_in[13];
    float* out = (float*)d_out;

    const int N = in_sizes[0] / 128;   // 100000 (multiple of 16)
    const int E = in_sizes[1] / 2;     // 3200000
    const int G = out_size / 10;       // 512
    const int NB = (N + (1 << BSH) - 1) >> BSH;   // 196 buckets of 512 nodes

    // workspace (256B-aligned chunks)
    char* wp = (char*)d_ws;
    auto alloc = [&](size_t bytes) {
        char* p = wp;
        wp += (bytes + 255) & ~(size_t)255;
        return p;
    };
    size_t qbytes = (size_t)N * 64 * 4;
    size_t rbytes = (size_t)NB * CAP * 8;
    // Q region double-duty: padded rec first, then conv outputs (rec dead by then)
    char*   Qreg    = alloc(qbytes > rbytes ? qbytes : rbytes);
    float*  Qf      = (float*)Qreg;
    bf16_t* Qb      = (bf16_t*)Qreg;
    int2*   rec     = (int2*)Qreg;
    bf16_t* P       = (bf16_t*)alloc((size_t)N * 64 * 2);
    int2*   meta    = (int2*) alloc(rbytes);          // padded, indexed via rbeg/rend
    int*    rbeg    = (int*)  alloc((size_t)N * 4);
    int*    rend    = (int*)  alloc((size_t)N * 4);
    float*  dinv    = (float*)alloc((size_t)N * 4);
    float*  pooled  = (float*)alloc((size_t)G * 64 * 4);
    int*    starts  = (int*)  alloc((size_t)(G + 1) * 4);
    int*    bcur    = (int*)  alloc((size_t)NB * 4);

    dim3 blk(256);
    dim3 g1024(1024);
    const int ntiles = N / 16;                         // 6250
    const int nblkB  = (E + BTILE - 1) / BTILE;        // 391
    const int nquads = (N + 3) / 4;                    // 25000
    dim3 gconv((nquads + 3) / 4);                      // 6250 blocks, 1 quad/wave

    // CSR build: bin into padded buckets -> per-bucket sort (+dinv, rbeg/rend)
    k_fill_i<<<dim3(1), blk, 0, stream>>>(bcur, 0, NB);
    k_passB<<<dim3(nblkB), dim3(512), 0, stream>>>(ei, ew, bcur, rec, E, NB);
    k_passC<<<dim3(NB), dim3(1024), 0, stream>>>(rec, bcur, rbeg, rend, dinv, meta, N);
    k_starts<<<dim3(4), blk, 0, stream>>>(batch, starts, N, G);

    // conv1 (K=128, f32 A)   [rec region is dead from here on; Q reuses it]
    k_gemm_mfma<128, true><<<g1024, blk, 0, stream>>>(x, W1, dinv, P, ntiles);
    k_conv4<false><<<gconv, blk, 0, stream>>>(P, rbeg, rend, meta, dinv, b1, Qb, nullptr, N);
    // conv2 (K=64, bf16 A)
    k_gemm_mfma<64, false><<<g1024, blk, 0, stream>>>(Qb, W2, dinv, P, ntiles);
    k_conv4<false><<<gconv, blk, 0, stream>>>(P, rbeg, rend, meta, dinv, b2, Qb, nullptr, N);
    // conv3 (K=64, bf16 A, f32 node output for pooling)
    k_gemm_mfma<64, false><<<g1024, blk, 0, stream>>>(Qb, W3, dinv, P, ntiles);
    k_conv4<true><<<gconv, blk, 0, stream>>>(P, rbeg, rend, meta, dinv, b3, nullptr, Qf, N);

    // pool + MLP
    k_pool<<<dim3(G), dim3(512), 0, stream>>>(Qf, starts, pooled, G);
    k_mlp<<<dim3(G), dim3(64), 0, stream>>>(pooled, fc1w, fc1b, fc2w, fc2b, out, G);
}